// Round 1
// 717.324 us; speedup vs baseline: 1.9886x; 1.9886x over previous
//
#include <hip/hip_runtime.h>
#include <cstdint>
#include <cstddef>

typedef __bf16 bf16;
typedef __bf16 bf16x8 __attribute__((ext_vector_type(8)));
typedef float f32x4 __attribute__((ext_vector_type(4)));

#define MFMA16(a, b, c) __builtin_amdgcn_mfma_f32_16x16x32_bf16((a), (b), (c), 0, 0, 0)

__device__ __forceinline__ float bf2f(bf16 v) { return (float)v; }

// ---- workspace layout (bytes) ----
#define OFF_SCALES 65536
#define OFF_FLAG   65552
#define OFF_QKVB   65600
#define OFF_PROJB  67136
#define OFF_N1W    67648
#define OFF_N1B    68160
#define OFF_FC1B   68672
#define OFF_FC2B   70720
#define OFF_N2W    71232
#define OFF_N2B    71744
#define OFF_QKVW   73728
#define OFF_PROJW  172032
#define OFF_FC1W   204800
#define OFF_FC2W   335872
#define OFF_X1BUF  524288

// ---- dtype-adaptive global load helper for the big input tensor only ----
template<int DT>
__device__ __forceinline__ void g_ld4(const void* base, size_t idx, float* o) {
    if constexpr (DT == 0) {
        uint2 d = *(const uint2*)((const bf16*)base + idx);
        const bf16* p = (const bf16*)&d;
        o[0] = bf2f(p[0]); o[1] = bf2f(p[1]); o[2] = bf2f(p[2]); o[3] = bf2f(p[3]);
    } else {
        float4 d = *(const float4*)((const float*)base + idx);
        o[0] = d.x; o[1] = d.y; o[2] = d.z; o[3] = d.w;
    }
}

// ---------------- kernel 0: dtype detect + CPB bias table + logit scales ----------------
__global__ void k_precompute(const void* __restrict__ cpb_w1, const void* __restrict__ cpb_b1,
                             const void* __restrict__ cpb_w2, const void* __restrict__ logit_scale,
                             const void* __restrict__ qkv_w_raw,
                             float* __restrict__ biasAll, float* __restrict__ scales,
                             int* __restrict__ flag)
{
    __shared__ float w1s[1024];
    __shared__ float b1s[512];
    __shared__ float w2s[2048];
    __shared__ float tabv[225][4];
    __shared__ int s_cnt;
    const int t = threadIdx.x;
    if (t == 0) s_cnt = 0;
    __syncthreads();
    {
        const unsigned short* u = (const unsigned short*)qkv_w_raw;
        int c = 0;
        for (int i = t; i < 1024; i += 256) {
            const int e = (u[i] >> 7) & 0xFF;
            if (e >= 0x90 || (e != 0 && e <= 0x60)) ++c;
        }
        atomicAdd(&s_cnt, c);
    }
    __syncthreads();
    const int isf = (s_cnt > 64) ? 1 : 0;
    if (t == 0) *flag = isf;
    if (isf) {
        const float* w1 = (const float*)cpb_w1;
        const float* b1 = (const float*)cpb_b1;
        const float* w2 = (const float*)cpb_w2;
        for (int i = t; i < 1024; i += 256) w1s[i] = w1[i];
        for (int i = t; i < 512;  i += 256) b1s[i] = b1[i];
        for (int i = t; i < 2048; i += 256) w2s[i] = w2[i];
        if (t < 4) scales[t] = expf(fminf(((const float*)logit_scale)[t], 4.6051701859880914f));
    } else {
        const bf16* w1 = (const bf16*)cpb_w1;
        const bf16* b1 = (const bf16*)cpb_b1;
        const bf16* w2 = (const bf16*)cpb_w2;
        for (int i = t; i < 1024; i += 256) w1s[i] = bf2f(w1[i]);
        for (int i = t; i < 512;  i += 256) b1s[i] = bf2f(b1[i]);
        for (int i = t; i < 2048; i += 256) w2s[i] = bf2f(w2[i]);
        if (t < 4) scales[t] = expf(fminf(bf2f(((const bf16*)logit_scale)[t]), 4.6051701859880914f));
    }
    __syncthreads();
    if (t < 225) {
        const int i = t / 15, j = t % 15;
        auto relf = [](int tt) -> float {
            float tf = (float)tt * (8.0f / 7.0f);
            float a = log2f(fabsf(tf) + 1.0f) * (1.0f / 3.0f);
            return tt < 0 ? -a : a;
        };
        const float x0 = relf(i - 7), x1 = relf(j - 7);
        float a0 = 0.f, a1 = 0.f, a2 = 0.f, a3 = 0.f;
        for (int jj = 0; jj < 512; ++jj) {
            float hv = w1s[jj*2] * x0 + w1s[jj*2+1] * x1 + b1s[jj];
            hv = fmaxf(hv, 0.0f);
            a0 += w2s[jj]        * hv;
            a1 += w2s[512 + jj]  * hv;
            a2 += w2s[1024 + jj] * hv;
            a3 += w2s[1536 + jj] * hv;
        }
        tabv[t][0] = a0; tabv[t][1] = a1; tabv[t][2] = a2; tabv[t][3] = a3;
    }
    __syncthreads();
    for (int idx = t; idx < 4*64*64; idx += 256) {
        const int h = idx >> 12, rem = idx & 4095, i = rem >> 6, j = rem & 63;
        const int di = (i >> 3) - (j >> 3) + 7;
        const int dj = (i & 7) - (j & 7) + 7;
        const float bv = tabv[di*15 + dj][h];
        biasAll[idx] = 16.0f / (1.0f + expf(-bv));
    }
}

// ---------------- kernel 0b: one-time weight/bias conversion into workspace ----------------
__global__ void k_convert(
    const void* __restrict__ qkv_w, const void* __restrict__ proj_w,
    const void* __restrict__ fc1w, const void* __restrict__ fc2w,
    const void* __restrict__ q_bias, const void* __restrict__ v_bias,
    const void* __restrict__ proj_b, const void* __restrict__ n1w, const void* __restrict__ n1b,
    const void* __restrict__ fc1b, const void* __restrict__ fc2b,
    const void* __restrict__ n2w, const void* __restrict__ n2b,
    const int* __restrict__ flag, char* __restrict__ ws)
{
    const int isf = *flag;
    const int g  = blockIdx.x * 256 + threadIdx.x;
    const int gs = gridDim.x * 256;
    bf16* qw = (bf16*)(ws + OFF_QKVW);
    bf16* pw = (bf16*)(ws + OFF_PROJW);
    bf16* f1 = (bf16*)(ws + OFF_FC1W);
    bf16* f2 = (bf16*)(ws + OFF_FC2W);
    if (isf) {
        const float* a = (const float*)qkv_w;  for (int i = g; i < 49152; i += gs) qw[i] = (bf16)a[i];
        const float* b = (const float*)proj_w; for (int i = g; i < 16384; i += gs) pw[i] = (bf16)b[i];
        const float* c = (const float*)fc1w;   for (int i = g; i < 65536; i += gs) f1[i] = (bf16)c[i];
        const float* d = (const float*)fc2w;   for (int i = g; i < 65536; i += gs) f2[i] = (bf16)d[i];
    } else {
        const bf16* a = (const bf16*)qkv_w;  for (int i = g; i < 49152; i += gs) qw[i] = a[i];
        const bf16* b = (const bf16*)proj_w; for (int i = g; i < 16384; i += gs) pw[i] = b[i];
        const bf16* c = (const bf16*)fc1w;   for (int i = g; i < 65536; i += gs) f1[i] = c[i];
        const bf16* d = (const bf16*)fc2w;   for (int i = g; i < 65536; i += gs) f2[i] = d[i];
    }
    auto ldf = [&](const void* p, int i) -> float {
        return isf ? ((const float*)p)[i] : bf2f(((const bf16*)p)[i]);
    };
    float* qb  = (float*)(ws + OFF_QKVB);
    float* pb  = (float*)(ws + OFF_PROJB);
    float* w1  = (float*)(ws + OFF_N1W);
    float* b1  = (float*)(ws + OFF_N1B);
    float* f1b = (float*)(ws + OFF_FC1B);
    float* f2b = (float*)(ws + OFF_FC2B);
    float* w2  = (float*)(ws + OFF_N2W);
    float* b2  = (float*)(ws + OFF_N2B);
    for (int i = g; i < 384; i += gs)
        qb[i] = (i < 128) ? ldf(q_bias, i) : ((i < 256) ? 0.0f : ldf(v_bias, i - 256));
    for (int i = g; i < 512; i += gs) f1b[i] = ldf(fc1b, i);
    for (int i = g; i < 128; i += gs) {
        pb[i]  = ldf(proj_b, i); w1[i] = ldf(n1w, i); b1[i] = ldf(n1b, i);
        f2b[i] = ldf(fc2b, i);   w2[i] = ldf(n2w, i); b2[i] = ldf(n2b, i);
    }
}

// ---------------- kernel 1: windowed attention + proj + LN + residual ----------------
// one block per (batch, window): 4096 blocks, 256 threads (wave w = head w)
// LDS 75008 B -> 2 blocks/CU (was ~124 KB -> 1 block/CU)
template<int DT>
__global__ __launch_bounds__(256, 2) void k_attn(
    const void* __restrict__ x,
    const bf16* __restrict__ qkvw, const float* __restrict__ qkvb,
    const bf16* __restrict__ projw, const float* __restrict__ projb,
    const float* __restrict__ n1wf, const float* __restrict__ n1bf,
    const float* __restrict__ biasAll, const float* __restrict__ scales,
    const int* __restrict__ flag, bf16* __restrict__ x1out)
{
    if (*flag != DT) return;

    __shared__ __align__(16) char smem[75008];
    bf16* Xs    = (bf16*)smem;                   // [64][136] window input / residual
    bf16* qkvs  = (bf16*)(smem + 17408);         // [64][264] q|k ; reuse: Ps[4][64][72] ; x1s[64][136]
    bf16* Ps    = qkvs;
    bf16* x1s   = qkvs;
    bf16* vs    = (bf16*)(smem + 54272);         // [128][72] v^T ; reuse: Os[64][136]
    bf16* Os    = vs;
    float* invqs = (float*)(smem + 72704);       // 256 ; reuse: LN partial sums
    float* invks = (float*)(smem + 73728);       // 256 ; reuse: LN partial sq-dev
    int*   rid   = (int*)(smem + 74752);         // 64

    const int tid  = threadIdx.x;
    const int wv   = tid >> 6;
    const int lane = tid & 63;
    const int l15  = lane & 15;
    const int quad = lane >> 4;

    const int bid = blockIdx.x;
    const int b   = bid >> 8;
    const int wh  = (bid >> 4) & 15;
    const int ww  = bid & 15;

    // ---- stage 0: gather shifted window into Xs[token][c]; region ids ----
    {
        const int c  = tid & 127;
        const int rb = tid >> 7;
        const int w0 = ww*8 + 4;
        const int w1 = (ww*8 + 8) & 127;
#pragma unroll
        for (int k = 0; k < 4; ++k) {
            const int r    = k*2 + rb;
            const int srch = (wh*8 + r + 4) & 127;
            const size_t rowbase = (((size_t)(b*128 + c))*128 + srch)*128;
            float va[4], vb[4];
            g_ld4<DT>(x, rowbase + w0, va);
            g_ld4<DT>(x, rowbase + w1, vb);
#pragma unroll
            for (int j = 0; j < 4; ++j) {
                Xs[(r*8 + j)*136 + c]     = (bf16)va[j];
                Xs[(r*8 + 4 + j)*136 + c] = (bf16)vb[j];
            }
        }
        if (tid < 64) {
            const int rr = tid >> 3, cc = tid & 7;
            const int hs = wh*8 + rr, wsc = ww*8 + cc;
            const int rh = (hs  < 120) ? 0 : ((hs  < 124) ? 1 : 2);
            const int rw = (wsc < 120) ? 0 : ((wsc < 124) ? 1 : 2);
            rid[tid] = rh*3 + rw;
        }
    }
    __syncthreads();

    // ---- stage 1: qkv = Xs @ qkv_w^T + bias; q,k -> qkvs; v -> vs (transposed) ----
    {
        f32x4 acc[4][6];
#pragma unroll
        for (int mt = 0; mt < 4; ++mt)
#pragma unroll
            for (int nl = 0; nl < 6; ++nl) acc[mt][nl] = (f32x4){0.f, 0.f, 0.f, 0.f};
#pragma unroll
        for (int ks = 0; ks < 4; ++ks) {
            bf16x8 a[4];
#pragma unroll
            for (int mt = 0; mt < 4; ++mt)
                a[mt] = *(const bf16x8*)&Xs[(mt*16 + l15)*136 + ks*32 + quad*8];
#pragma unroll
            for (int nl = 0; nl < 6; ++nl) {
                const int o = (wv*6 + nl)*16 + l15;
                bf16x8 bw = *(const bf16x8*)&qkvw[(size_t)o*128 + ks*32 + quad*8];
#pragma unroll
                for (int mt = 0; mt < 4; ++mt)
                    acc[mt][nl] = MFMA16(a[mt], bw, acc[mt][nl]);
            }
        }
#pragma unroll
        for (int nl = 0; nl < 6; ++nl) {
            const int col = (wv*6 + nl)*16 + l15;
            const float bias = qkvb[col];
#pragma unroll
            for (int mt = 0; mt < 4; ++mt)
#pragma unroll
                for (int r = 0; r < 4; ++r) {
                    const int row = mt*16 + quad*4 + r;
                    const float v = acc[mt][nl][r] + bias;
                    if (col < 256) qkvs[row*264 + col] = (bf16)v;       // tile-uniform branch
                    else           vs[(col - 256)*72 + row] = (bf16)v;
                }
        }
    }
    __syncthreads();

    // ---- stage 2: per-head q/k row L2 norms (wave = head, lane = token) ----
    {
        const int n = lane;
        const bf16* qrow = &qkvs[n*264 + wv*32];
        const bf16* krow = &qkvs[n*264 + 128 + wv*32];
        float sq = 0.f, sk = 0.f;
#pragma unroll
        for (int dd = 0; dd < 4; ++dd) {
            bf16x8 vq = *(const bf16x8*)(qrow + dd*8);
            bf16x8 vk = *(const bf16x8*)(krow + dd*8);
#pragma unroll
            for (int e = 0; e < 8; ++e) {
                const float fq = (float)vq[e]; sq += fq*fq;
                const float fk = (float)vk[e]; sk += fk*fk;
            }
        }
        invqs[wv*64 + n] = 1.0f / fmaxf(sqrtf(sq), 1e-12f);
        invks[wv*64 + n] = 1.0f / fmaxf(sqrtf(sk), 1e-12f);
    }
    __syncthreads();

    // ---- stage 3: S = scale*(q.k)*invq*invk + bias + mask; softmax; P -> LDS (over qkvs) ----
    {
        const float scale = scales[wv];
        f32x4 s[4][4];
#pragma unroll
        for (int mt = 0; mt < 4; ++mt)
#pragma unroll
            for (int nt = 0; nt < 4; ++nt) s[mt][nt] = (f32x4){0.f, 0.f, 0.f, 0.f};
        bf16x8 aq[4];
#pragma unroll
        for (int mt = 0; mt < 4; ++mt)
            aq[mt] = *(const bf16x8*)&qkvs[(mt*16 + l15)*264 + wv*32 + quad*8];
#pragma unroll
        for (int nt = 0; nt < 4; ++nt) {
            bf16x8 bk = *(const bf16x8*)&qkvs[(nt*16 + l15)*264 + 128 + wv*32 + quad*8];
#pragma unroll
            for (int mt = 0; mt < 4; ++mt)
                s[mt][nt] = MFMA16(aq[mt], bk, s[mt][nt]);
        }
        __syncthreads();   // all waves done reading q/k before P overlays qkvs
        const float* bg = biasAll + wv*4096;
        const bool bnd = (wh == 15) || (ww == 15);
        float ikj[4]; int rj[4];
#pragma unroll
        for (int nt = 0; nt < 4; ++nt) {
            ikj[nt] = invks[wv*64 + nt*16 + l15];
            rj[nt]  = rid[nt*16 + l15];
        }
#pragma unroll
        for (int mt = 0; mt < 4; ++mt)
#pragma unroll
            for (int r = 0; r < 4; ++r) {
                const int i = mt*16 + quad*4 + r;
                const float iqs = invqs[wv*64 + i] * scale;
                const int ri = rid[i];
#pragma unroll
                for (int nt = 0; nt < 4; ++nt) {
                    const int j = nt*16 + l15;
                    float v = s[mt][nt][r] * (iqs * ikj[nt]) + bg[i*64 + j];
                    if (bnd && (ri != rj[nt])) v -= 100.0f;
                    s[mt][nt][r] = v;
                }
            }
        // softmax over j (16 lanes of the quad x 4 n-tiles)
#pragma unroll
        for (int mt = 0; mt < 4; ++mt) {
            float mx[4], sm[4];
#pragma unroll
            for (int r = 0; r < 4; ++r) {
                float m = fmaxf(fmaxf(s[mt][0][r], s[mt][1][r]), fmaxf(s[mt][2][r], s[mt][3][r]));
                m = fmaxf(m, __shfl_xor(m, 1));
                m = fmaxf(m, __shfl_xor(m, 2));
                m = fmaxf(m, __shfl_xor(m, 4));
                m = fmaxf(m, __shfl_xor(m, 8));
                mx[r] = m; sm[r] = 0.f;
            }
#pragma unroll
            for (int nt = 0; nt < 4; ++nt)
#pragma unroll
                for (int r = 0; r < 4; ++r) {
                    const float e = __expf(s[mt][nt][r] - mx[r]);
                    s[mt][nt][r] = e;
                    sm[r] += e;
                }
#pragma unroll
            for (int r = 0; r < 4; ++r) {
                float t2 = sm[r];
                t2 += __shfl_xor(t2, 1);
                t2 += __shfl_xor(t2, 2);
                t2 += __shfl_xor(t2, 4);
                t2 += __shfl_xor(t2, 8);
                sm[r] = 1.0f / t2;
            }
#pragma unroll
            for (int nt = 0; nt < 4; ++nt)
#pragma unroll
                for (int r = 0; r < 4; ++r) {
                    const float p = s[mt][nt][r] * sm[r];
                    Ps[wv*64*72 + (mt*16 + quad*4 + r)*72 + nt*16 + l15] = (bf16)p;
                }
        }
    }
    __syncthreads();

    // ---- stage 4: O = P @ V -> Os (overlays vs after barrier) ----
    {
        f32x4 o[4][2];
#pragma unroll
        for (int mt = 0; mt < 4; ++mt)
#pragma unroll
            for (int nt = 0; nt < 2; ++nt) o[mt][nt] = (f32x4){0.f, 0.f, 0.f, 0.f};
#pragma unroll
        for (int ks = 0; ks < 2; ++ks) {
            bf16x8 ap[4];
#pragma unroll
            for (int mt = 0; mt < 4; ++mt)
                ap[mt] = *(const bf16x8*)&Ps[wv*64*72 + (mt*16 + l15)*72 + ks*32 + quad*8];
#pragma unroll
            for (int nt = 0; nt < 2; ++nt) {
                bf16x8 bv = *(const bf16x8*)&vs[(wv*32 + nt*16 + l15)*72 + ks*32 + quad*8];
#pragma unroll
                for (int mt = 0; mt < 4; ++mt)
                    o[mt][nt] = MFMA16(ap[mt], bv, o[mt][nt]);
            }
        }
        __syncthreads();   // all waves done reading vs before Os overlays it
#pragma unroll
        for (int mt = 0; mt < 4; ++mt)
#pragma unroll
            for (int nt = 0; nt < 2; ++nt)
#pragma unroll
                for (int r = 0; r < 4; ++r) {
                    const int i = mt*16 + quad*4 + r;
                    Os[i*136 + wv*32 + nt*16 + l15] = (bf16)o[mt][nt][r];
                }
    }
    __syncthreads();

    // ---- stage 5: proj (waves own 32 output cols, 4 MFMA per B-load) + LN + residual ----
    {
        f32x4 pa[4][2];
#pragma unroll
        for (int mt = 0; mt < 4; ++mt)
#pragma unroll
            for (int nt = 0; nt < 2; ++nt) pa[mt][nt] = (f32x4){0.f, 0.f, 0.f, 0.f};
#pragma unroll
        for (int ks = 0; ks < 4; ++ks) {
            bf16x8 ao[4];
#pragma unroll
            for (int mt = 0; mt < 4; ++mt)
                ao[mt] = *(const bf16x8*)&Os[(mt*16 + l15)*136 + ks*32 + quad*8];
#pragma unroll
            for (int nt = 0; nt < 2; ++nt) {
                const int oc = wv*32 + nt*16 + l15;
                bf16x8 bw = *(const bf16x8*)&projw[(size_t)oc*128 + ks*32 + quad*8];
#pragma unroll
                for (int mt = 0; mt < 4; ++mt)
                    pa[mt][nt] = MFMA16(ao[mt], bw, pa[mt][nt]);
            }
        }
        float pb[2], wn[2], bn[2];
#pragma unroll
        for (int nt = 0; nt < 2; ++nt) {
            const int oc = wv*32 + nt*16 + l15;
            pb[nt] = projb[oc]; wn[nt] = n1wf[oc]; bn[nt] = n1bf[oc];
        }
        float* ps = invqs;   // dead after stage 3
        float* pq = invks;
        // pass 1: per-wave partial sums over its 32 cols
#pragma unroll
        for (int mt = 0; mt < 4; ++mt)
#pragma unroll
            for (int r = 0; r < 4; ++r) {
                pa[mt][0][r] += pb[0];
                pa[mt][1][r] += pb[1];
                float sv = pa[mt][0][r] + pa[mt][1][r];
                sv += __shfl_xor(sv, 1); sv += __shfl_xor(sv, 2);
                sv += __shfl_xor(sv, 4); sv += __shfl_xor(sv, 8);
                if (l15 == 0) ps[wv*64 + mt*16 + quad*4 + r] = sv;
            }
        __syncthreads();
        float mu[4][4];
#pragma unroll
        for (int mt = 0; mt < 4; ++mt)
#pragma unroll
            for (int r = 0; r < 4; ++r) {
                const int i = mt*16 + quad*4 + r;
                mu[mt][r] = (ps[i] + ps[64+i] + ps[128+i] + ps[192+i]) * (1.0f/128.0f);
                const float d0 = pa[mt][0][r] - mu[mt][r];
                const float d1 = pa[mt][1][r] - mu[mt][r];
                float sv = d0*d0 + d1*d1;
                sv += __shfl_xor(sv, 1); sv += __shfl_xor(sv, 2);
                sv += __shfl_xor(sv, 4); sv += __shfl_xor(sv, 8);
                if (l15 == 0) pq[wv*64 + i] = sv;
            }
        __syncthreads();
#pragma unroll
        for (int mt = 0; mt < 4; ++mt)
#pragma unroll
            for (int r = 0; r < 4; ++r) {
                const int i = mt*16 + quad*4 + r;
                const float var = (pq[i] + pq[64+i] + pq[128+i] + pq[192+i]) * (1.0f/128.0f);
                const float rstd = rsqrtf(var + 1e-5f);
#pragma unroll
                for (int nt = 0; nt < 2; ++nt) {
                    const int oc = wv*32 + nt*16 + l15;
                    const float y = (pa[mt][nt][r] - mu[mt][r]) * rstd * wn[nt] + bn[nt];
                    const float x1v = bf2f(Xs[i*136 + oc]) + y;
                    x1s[i*136 + oc] = (bf16)x1v;     // x1s overlays qkvs/Ps (dead)
                }
            }
    }
    __syncthreads();

    // ---- stage 6: write x1 tile to global (reverse-shifted final positions) ----
    {
        const int n = tid >> 2, part = tid & 3;
        const int rr = n >> 3, cc = n & 7;
        const int hf = (wh*8 + rr + 4) & 127;
        const int wf = (ww*8 + cc + 4) & 127;
        bf16* dst = x1out + ((size_t)b*16384 + hf*128 + wf)*128 + part*32;
        const uint4* srcq = (const uint4*)&x1s[n*136 + part*32];
#pragma unroll
        for (int k2 = 0; k2 < 4; ++k2)
            ((uint4*)dst)[k2] = srcq[k2];
    }
}

// ---------------- kernel 2: MLP + LN(norm2) + residual, planar output ----------------
// 4096 blocks x 64 tokens, 256 threads; hidden chunked 4x128; LDS 36864 -> 4 blocks/CU
template<int DT>
__global__ __launch_bounds__(256, 4) void k_mlp(
    const bf16* __restrict__ x1, const bf16* __restrict__ fc1w, const float* __restrict__ fc1bf,
    const bf16* __restrict__ fc2w, const float* __restrict__ fc2bf,
    const float* __restrict__ n2wf, const float* __restrict__ n2bf,
    const int* __restrict__ flag, void* __restrict__ out)
{
    if (*flag != DT) return;

    __shared__ __align__(16) bf16 x1s[64*136];
    __shared__ __align__(16) bf16 hs[64*136];   // fc1 chunk; reused as x2 staging
    __shared__ float ps[256];
    __shared__ float pq[256];

    const int tid  = threadIdx.x;
    const int wv   = tid >> 6;
    const int lane = tid & 63;
    const int l15  = lane & 15;
    const int quad = lane >> 4;
    const int bid  = blockIdx.x;

    {
        const int n = tid >> 2, part = tid & 3;
        const uint4* src = (const uint4*)(x1 + ((size_t)bid*64 + n)*128 + part*32);
        uint4* dst = (uint4*)&x1s[n*136 + part*32];
#pragma unroll
        for (int k = 0; k < 4; ++k) dst[k] = src[k];
    }
    __syncthreads();

    f32x4 ya[4][2];
#pragma unroll
    for (int mt = 0; mt < 4; ++mt)
#pragma unroll
        for (int nt = 0; nt < 2; ++nt) ya[mt][nt] = (f32x4){0.f, 0.f, 0.f, 0.f};

#pragma unroll
    for (int ch = 0; ch < 4; ++ch) {
        if (ch) __syncthreads();   // previous chunk's fc2 reads of hs must finish
        // fc1 chunk: 64 tokens x 128 hidden (wave owns 32 hidden cols)
        f32x4 ha[4][2];
#pragma unroll
        for (int mt = 0; mt < 4; ++mt)
#pragma unroll
            for (int nt = 0; nt < 2; ++nt) ha[mt][nt] = (f32x4){0.f, 0.f, 0.f, 0.f};
#pragma unroll
        for (int ks = 0; ks < 4; ++ks) {
            bf16x8 a[4];
#pragma unroll
            for (int mt = 0; mt < 4; ++mt)
                a[mt] = *(const bf16x8*)&x1s[(mt*16 + l15)*136 + ks*32 + quad*8];
#pragma unroll
            for (int nt = 0; nt < 2; ++nt) {
                const int hid = ch*128 + wv*32 + nt*16 + l15;
                bf16x8 bw = *(const bf16x8*)&fc1w[(size_t)hid*128 + ks*32 + quad*8];
#pragma unroll
                for (int mt = 0; mt < 4; ++mt)
                    ha[mt][nt] = MFMA16(a[mt], bw, ha[mt][nt]);
            }
        }
#pragma unroll
        for (int nt = 0; nt < 2; ++nt) {
            const int hid = ch*128 + wv*32 + nt*16 + l15;
            const float bb = fc1bf[hid];
            const int hl = wv*32 + nt*16 + l15;
#pragma unroll
            for (int mt = 0; mt < 4; ++mt)
#pragma unroll
                for (int r = 0; r < 4; ++r) {
                    float v = ha[mt][nt][r] + bb;
                    v = v / (1.0f + __expf(-v));   // silu
                    hs[(mt*16 + quad*4 + r)*136 + hl] = (bf16)v;
                }
        }
        __syncthreads();
        // fc2 partial: wave owns 32 OUTPUT cols, all 64 tokens (4 MFMA per B-load, no redundancy)
#pragma unroll
        for (int ks = 0; ks < 4; ++ks) {
            bf16x8 ah[4];
#pragma unroll
            for (int mt = 0; mt < 4; ++mt)
                ah[mt] = *(const bf16x8*)&hs[(mt*16 + l15)*136 + ks*32 + quad*8];
#pragma unroll
            for (int nt = 0; nt < 2; ++nt) {
                const int oc = wv*32 + nt*16 + l15;
                bf16x8 bw = *(const bf16x8*)&fc2w[(size_t)oc*512 + ch*128 + ks*32 + quad*8];
#pragma unroll
                for (int mt = 0; mt < 4; ++mt)
                    ya[mt][nt] = MFMA16(ah[mt], bw, ya[mt][nt]);
            }
        }
    }
    __syncthreads();   // all fc2 reads of hs done before reuse as x2 staging

    // ---- bias + LN(norm2) via cross-wave partials + residual -> x2 staging (hs) ----
    {
        float pb[2], wn[2], bn[2];
#pragma unroll
        for (int nt = 0; nt < 2; ++nt) {
            const int oc = wv*32 + nt*16 + l15;
            pb[nt] = fc2bf[oc]; wn[nt] = n2wf[oc]; bn[nt] = n2bf[oc];
        }
#pragma unroll
        for (int mt = 0; mt < 4; ++mt)
#pragma unroll
            for (int r = 0; r < 4; ++r) {
                ya[mt][0][r] += pb[0];
                ya[mt][1][r] += pb[1];
                float sv = ya[mt][0][r] + ya[mt][1][r];
                sv += __shfl_xor(sv, 1); sv += __shfl_xor(sv, 2);
                sv += __shfl_xor(sv, 4); sv += __shfl_xor(sv, 8);
                if (l15 == 0) ps[wv*64 + mt*16 + quad*4 + r] = sv;
            }
        __syncthreads();
        float mu[4][4];
#pragma unroll
        for (int mt = 0; mt < 4; ++mt)
#pragma unroll
            for (int r = 0; r < 4; ++r) {
                const int i = mt*16 + quad*4 + r;
                mu[mt][r] = (ps[i] + ps[64+i] + ps[128+i] + ps[192+i]) * (1.0f/128.0f);
                const float d0 = ya[mt][0][r] - mu[mt][r];
                const float d1 = ya[mt][1][r] - mu[mt][r];
                float sv = d0*d0 + d1*d1;
                sv += __shfl_xor(sv, 1); sv += __shfl_xor(sv, 2);
                sv += __shfl_xor(sv, 4); sv += __shfl_xor(sv, 8);
                if (l15 == 0) pq[wv*64 + i] = sv;
            }
        __syncthreads();
        bf16* x2s = hs;
#pragma unroll
        for (int mt = 0; mt < 4; ++mt)
#pragma unroll
            for (int r = 0; r < 4; ++r) {
                const int i = mt*16 + quad*4 + r;
                const float var = (pq[i] + pq[64+i] + pq[128+i] + pq[192+i]) * (1.0f/128.0f);
                const float rstd = rsqrtf(var + 1e-5f);
#pragma unroll
                for (int nt = 0; nt < 2; ++nt) {
                    const int oc = wv*32 + nt*16 + l15;
                    const float yv = (ya[mt][nt][r] - mu[mt][r]) * rstd * wn[nt] + bn[nt];
                    const float x2v = bf2f(x1s[i*136 + oc]) + yv;
                    x2s[i*136 + oc] = (bf16)x2v;
                }
            }
    }
    __syncthreads();

    // transpose-out: (token, c) -> planar (B, C, H, W), coalesced stores
    {
        const int c = tid >> 1, half = tid & 1;
        const int b = bid >> 8, rem = bid & 255;
        const int hh = rem >> 1, w0 = (rem & 1)*64;
        const bf16* x2s = hs;
        const size_t base_off = ((size_t)(b*128 + c))*16384 + hh*128 + w0 + half*32;
        if constexpr (DT == 0) {
            const unsigned short* x2u = (const unsigned short*)hs;
            bf16* dst = (bf16*)out + base_off;
#pragma unroll
            for (int g = 0; g < 4; ++g) {
                const int tb = half*32 + g*8;
                uint4 u;
                u.x = (unsigned)x2u[(tb+0)*136 + c] | ((unsigned)x2u[(tb+1)*136 + c] << 16);
                u.y = (unsigned)x2u[(tb+2)*136 + c] | ((unsigned)x2u[(tb+3)*136 + c] << 16);
                u.z = (unsigned)x2u[(tb+4)*136 + c] | ((unsigned)x2u[(tb+5)*136 + c] << 16);
                u.w = (unsigned)x2u[(tb+6)*136 + c] | ((unsigned)x2u[(tb+7)*136 + c] << 16);
                ((uint4*)dst)[g] = u;
            }
        } else {
            float* dst = (float*)out + base_off;
#pragma unroll
            for (int g = 0; g < 4; ++g) {
                const int tb = half*32 + g*8;
                float4 u0, u1;
                u0.x = bf2f(x2s[(tb+0)*136 + c]); u0.y = bf2f(x2s[(tb+1)*136 + c]);
                u0.z = bf2f(x2s[(tb+2)*136 + c]); u0.w = bf2f(x2s[(tb+3)*136 + c]);
                u1.x = bf2f(x2s[(tb+4)*136 + c]); u1.y = bf2f(x2s[(tb+5)*136 + c]);
                u1.z = bf2f(x2s[(tb+6)*136 + c]); u1.w = bf2f(x2s[(tb+7)*136 + c]);
                ((float4*)dst)[2*g]     = u0;
                ((float4*)dst)[2*g + 1] = u1;
            }
        }
    }
}

extern "C" void kernel_launch(void* const* d_in, const int* in_sizes, int n_in,
                              void* d_out, int out_size, void* d_ws, size_t ws_size,
                              hipStream_t stream)
{
    (void)in_sizes; (void)n_in; (void)out_size; (void)ws_size;
    const void* x      = d_in[0];
    const void* n1w    = d_in[1];
    const void* n1b    = d_in[2];
    const void* qkv_w  = d_in[3];
    const void* q_bias = d_in[4];
    const void* v_bias = d_in[5];
    const void* lscale = d_in[6];
    const void* cpb_w1 = d_in[7];
    const void* cpb_b1 = d_in[8];
    const void* cpb_w2 = d_in[9];
    const void* proj_w = d_in[10];
    const void* proj_b = d_in[11];
    const void* n2w    = d_in[12];
    const void* n2b    = d_in[13];
    const void* fc1w   = d_in[14];
    const void* fc1b   = d_in[15];
    const void* fc2w   = d_in[16];
    const void* fc2b   = d_in[17];

    char*  ws      = (char*)d_ws;
    float* biasAll = (float*)ws;                      // 64 KiB @ 0
    float* scales  = (float*)(ws + OFF_SCALES);
    int*   flag    = (int*)(ws + OFF_FLAG);
    bf16*  x1buf   = (bf16*)(ws + OFF_X1BUF);         // 64 MiB

    k_precompute<<<dim3(1), dim3(256), 0, stream>>>(cpb_w1, cpb_b1, cpb_w2, lscale, qkv_w,
                                                    biasAll, scales, flag);
    k_convert<<<dim3(96), dim3(256), 0, stream>>>(qkv_w, proj_w, fc1w, fc2w,
                                                  q_bias, v_bias, proj_b, n1w, n1b,
                                                  fc1b, fc2b, n2w, n2b, flag, ws);
    k_attn<0><<<dim3(4096), dim3(256), 0, stream>>>(x,
        (const bf16*)(ws + OFF_QKVW), (const float*)(ws + OFF_QKVB),
        (const bf16*)(ws + OFF_PROJW), (const float*)(ws + OFF_PROJB),
        (const float*)(ws + OFF_N1W), (const float*)(ws + OFF_N1B),
        biasAll, scales, flag, x1buf);
    k_attn<1><<<dim3(4096), dim3(256), 0, stream>>>(x,
        (const bf16*)(ws + OFF_QKVW), (const float*)(ws + OFF_QKVB),
        (const bf16*)(ws + OFF_PROJW), (const float*)(ws + OFF_PROJB),
        (const float*)(ws + OFF_N1W), (const float*)(ws + OFF_N1B),
        biasAll, scales, flag, x1buf);
    k_mlp<0><<<dim3(4096), dim3(256), 0, stream>>>(x1buf,
        (const bf16*)(ws + OFF_FC1W), (const float*)(ws + OFF_FC1B),
        (const bf16*)(ws + OFF_FC2W), (const float*)(ws + OFF_FC2B),
        (const float*)(ws + OFF_N2W), (const float*)(ws + OFF_N2B), flag, d_out);
    k_mlp<1><<<dim3(4096), dim3(256), 0, stream>>>(x1buf,
        (const bf16*)(ws + OFF_FC1W), (const float*)(ws + OFF_FC1B),
        (const bf16*)(ws + OFF_FC2W), (const float*)(ws + OFF_FC2B),
        (const float*)(ws + OFF_N2W), (const float*)(ws + OFF_N2B), flag, d_out);
}

// Round 2
// 701.390 us; speedup vs baseline: 2.0338x; 1.0227x over previous
//
#include <hip/hip_runtime.h>
#include <cstdint>
#include <cstddef>

typedef __bf16 bf16;
typedef __bf16 bf16x8 __attribute__((ext_vector_type(8)));
typedef float f32x4 __attribute__((ext_vector_type(4)));

#define MFMA16(a, b, c) __builtin_amdgcn_mfma_f32_16x16x32_bf16((a), (b), (c), 0, 0, 0)

__device__ __forceinline__ float bf2f(bf16 v) { return (float)v; }

// ---- workspace layout (bytes) ----
#define OFF_SCALES 65536
#define OFF_FLAG   65552
#define OFF_QKVB   65600
#define OFF_PROJB  67136
#define OFF_N1W    67648
#define OFF_N1B    68160
#define OFF_FC1B   68672
#define OFF_FC2B   70720
#define OFF_N2W    71232
#define OFF_N2B    71744
#define OFF_QKVW   73728
#define OFF_PROJW  172032
#define OFF_FC1W   204800
#define OFF_FC2W   335872

// ---- dtype-adaptive global load helper for the big input tensor only ----
template<int DT>
__device__ __forceinline__ void g_ld4(const void* base, size_t idx, float* o) {
    if constexpr (DT == 0) {
        uint2 d = *(const uint2*)((const bf16*)base + idx);
        const bf16* p = (const bf16*)&d;
        o[0] = bf2f(p[0]); o[1] = bf2f(p[1]); o[2] = bf2f(p[2]); o[3] = bf2f(p[3]);
    } else {
        float4 d = *(const float4*)((const float*)base + idx);
        o[0] = d.x; o[1] = d.y; o[2] = d.z; o[3] = d.w;
    }
}

// ---------------- kernel 0: dtype detect + CPB bias table + logit scales ----------------
__global__ void k_precompute(const void* __restrict__ cpb_w1, const void* __restrict__ cpb_b1,
                             const void* __restrict__ cpb_w2, const void* __restrict__ logit_scale,
                             const void* __restrict__ qkv_w_raw,
                             float* __restrict__ biasAll, float* __restrict__ scales,
                             int* __restrict__ flag)
{
    __shared__ float w1s[1024];
    __shared__ float b1s[512];
    __shared__ float w2s[2048];
    __shared__ float tabv[225][4];
    __shared__ int s_cnt;
    const int t = threadIdx.x;
    if (t == 0) s_cnt = 0;
    __syncthreads();
    {
        const unsigned short* u = (const unsigned short*)qkv_w_raw;
        int c = 0;
        for (int i = t; i < 1024; i += 256) {
            const int e = (u[i] >> 7) & 0xFF;
            if (e >= 0x90 || (e != 0 && e <= 0x60)) ++c;
        }
        atomicAdd(&s_cnt, c);
    }
    __syncthreads();
    const int isf = (s_cnt > 64) ? 1 : 0;
    if (t == 0) *flag = isf;
    if (isf) {
        const float* w1 = (const float*)cpb_w1;
        const float* b1 = (const float*)cpb_b1;
        const float* w2 = (const float*)cpb_w2;
        for (int i = t; i < 1024; i += 256) w1s[i] = w1[i];
        for (int i = t; i < 512;  i += 256) b1s[i] = b1[i];
        for (int i = t; i < 2048; i += 256) w2s[i] = w2[i];
        if (t < 4) scales[t] = expf(fminf(((const float*)logit_scale)[t], 4.6051701859880914f));
    } else {
        const bf16* w1 = (const bf16*)cpb_w1;
        const bf16* b1 = (const bf16*)cpb_b1;
        const bf16* w2 = (const bf16*)cpb_w2;
        for (int i = t; i < 1024; i += 256) w1s[i] = bf2f(w1[i]);
        for (int i = t; i < 512;  i += 256) b1s[i] = bf2f(b1[i]);
        for (int i = t; i < 2048; i += 256) w2s[i] = bf2f(w2[i]);
        if (t < 4) scales[t] = expf(fminf(bf2f(((const bf16*)logit_scale)[t]), 4.6051701859880914f));
    }
    __syncthreads();
    if (t < 225) {
        const int i = t / 15, j = t % 15;
        auto relf = [](int tt) -> float {
            float tf = (float)tt * (8.0f / 7.0f);
            float a = log2f(fabsf(tf) + 1.0f) * (1.0f / 3.0f);
            return tt < 0 ? -a : a;
        };
        const float x0 = relf(i - 7), x1 = relf(j - 7);
        float a0 = 0.f, a1 = 0.f, a2 = 0.f, a3 = 0.f;
        for (int jj = 0; jj < 512; ++jj) {
            float hv = w1s[jj*2] * x0 + w1s[jj*2+1] * x1 + b1s[jj];
            hv = fmaxf(hv, 0.0f);
            a0 += w2s[jj]        * hv;
            a1 += w2s[512 + jj]  * hv;
            a2 += w2s[1024 + jj] * hv;
            a3 += w2s[1536 + jj] * hv;
        }
        tabv[t][0] = a0; tabv[t][1] = a1; tabv[t][2] = a2; tabv[t][3] = a3;
    }
    __syncthreads();
    for (int idx = t; idx < 4*64*64; idx += 256) {
        const int h = idx >> 12, rem = idx & 4095, i = rem >> 6, j = rem & 63;
        const int di = (i >> 3) - (j >> 3) + 7;
        const int dj = (i & 7) - (j & 7) + 7;
        const float bv = tabv[di*15 + dj][h];
        biasAll[idx] = 16.0f / (1.0f + expf(-bv));
    }
}

// ---------------- kernel 0b: one-time weight/bias conversion into workspace ----------------
__global__ void k_convert(
    const void* __restrict__ qkv_w, const void* __restrict__ proj_w,
    const void* __restrict__ fc1w, const void* __restrict__ fc2w,
    const void* __restrict__ q_bias, const void* __restrict__ v_bias,
    const void* __restrict__ proj_b, const void* __restrict__ n1w, const void* __restrict__ n1b,
    const void* __restrict__ fc1b, const void* __restrict__ fc2b,
    const void* __restrict__ n2w, const void* __restrict__ n2b,
    const int* __restrict__ flag, char* __restrict__ ws)
{
    const int isf = *flag;
    const int g  = blockIdx.x * 256 + threadIdx.x;
    const int gs = gridDim.x * 256;
    bf16* qw = (bf16*)(ws + OFF_QKVW);
    bf16* pw = (bf16*)(ws + OFF_PROJW);
    bf16* f1 = (bf16*)(ws + OFF_FC1W);
    bf16* f2 = (bf16*)(ws + OFF_FC2W);
    if (isf) {
        const float* a = (const float*)qkv_w;  for (int i = g; i < 49152; i += gs) qw[i] = (bf16)a[i];
        const float* b = (const float*)proj_w; for (int i = g; i < 16384; i += gs) pw[i] = (bf16)b[i];
        const float* c = (const float*)fc1w;   for (int i = g; i < 65536; i += gs) f1[i] = (bf16)c[i];
        const float* d = (const float*)fc2w;   for (int i = g; i < 65536; i += gs) f2[i] = (bf16)d[i];
    } else {
        const bf16* a = (const bf16*)qkv_w;  for (int i = g; i < 49152; i += gs) qw[i] = a[i];
        const bf16* b = (const bf16*)proj_w; for (int i = g; i < 16384; i += gs) pw[i] = b[i];
        const bf16* c = (const bf16*)fc1w;   for (int i = g; i < 65536; i += gs) f1[i] = c[i];
        const bf16* d = (const bf16*)fc2w;   for (int i = g; i < 65536; i += gs) f2[i] = d[i];
    }
    auto ldf = [&](const void* p, int i) -> float {
        return isf ? ((const float*)p)[i] : bf2f(((const bf16*)p)[i]);
    };
    float* qb  = (float*)(ws + OFF_QKVB);
    float* pb  = (float*)(ws + OFF_PROJB);
    float* w1  = (float*)(ws + OFF_N1W);
    float* b1  = (float*)(ws + OFF_N1B);
    float* f1b = (float*)(ws + OFF_FC1B);
    float* f2b = (float*)(ws + OFF_FC2B);
    float* w2  = (float*)(ws + OFF_N2W);
    float* b2  = (float*)(ws + OFF_N2B);
    for (int i = g; i < 384; i += gs)
        qb[i] = (i < 128) ? ldf(q_bias, i) : ((i < 256) ? 0.0f : ldf(v_bias, i - 256));
    for (int i = g; i < 512; i += gs) f1b[i] = ldf(fc1b, i);
    for (int i = g; i < 128; i += gs) {
        pb[i]  = ldf(proj_b, i); w1[i] = ldf(n1w, i); b1[i] = ldf(n1b, i);
        f2b[i] = ldf(fc2b, i);   w2[i] = ldf(n2w, i); b2[i] = ldf(n2b, i);
    }
}

// ---------------- kernel 1: FULLY FUSED layer: attn + proj + LN1 + residual + MLP + LN2 ----------------
// one block per (batch, window): 4096 blocks, 256 threads (wave = head for attn)
// LDS 75008 B -> 2 blocks/CU. XCD-swizzled blockIdx for L2 locality of x reads / out writes.
template<int DT>
__global__ __launch_bounds__(256, 2) void k_fused(
    const void* __restrict__ x,
    const bf16* __restrict__ qkvw, const float* __restrict__ qkvb,
    const bf16* __restrict__ projw, const float* __restrict__ projb,
    const float* __restrict__ n1wf, const float* __restrict__ n1bf,
    const bf16* __restrict__ fc1w, const float* __restrict__ fc1bf,
    const bf16* __restrict__ fc2w, const float* __restrict__ fc2bf,
    const float* __restrict__ n2wf, const float* __restrict__ n2bf,
    const float* __restrict__ biasAll, const float* __restrict__ scales,
    const int* __restrict__ flag, void* __restrict__ out)
{
    if (*flag != DT) return;

    __shared__ __align__(16) char smem[75008];
    bf16* Xs    = (bf16*)smem;                   // [64][136] window input / residual
    bf16* qkvs  = (bf16*)(smem + 17408);         // [64][264] q|k ; reuse: Ps[4][64][72] ; x1s[64][136]
    bf16* Ps    = qkvs;
    bf16* x1s   = qkvs;
    bf16* vs    = (bf16*)(smem + 54272);         // [128][72] v^T ; reuse: Os[64][136] ; hs[64][136] ; x2s
    bf16* Os    = vs;
    bf16* hs    = vs;
    float* invqs = (float*)(smem + 72704);       // 256 ; reuse: LN partial sums (ps)
    float* invks = (float*)(smem + 73728);       // 256 ; reuse: LN partial sq-dev (pq)
    int*   rid   = (int*)(smem + 74752);         // 64
    float* psum = invqs;
    float* pvar = invks;

    const int tid  = threadIdx.x;
    const int wv   = tid >> 6;
    const int lane = tid & 63;
    const int l15  = lane & 15;
    const int quad = lane >> 4;

    // XCD-aware bijective swizzle: hw-consecutive blocks (round-robin over 8 XCDs)
    // get logical-contiguous chunks -> the 16 blocks sharing (b, wh) co-locate on one XCD.
    const int bid0 = blockIdx.x;
    const int bid  = ((bid0 & 7) << 9) | (bid0 >> 3);
    const int b   = bid >> 8;
    const int wh  = (bid >> 4) & 15;
    const int ww  = bid & 15;

    // ---- stage 0: gather shifted window into Xs[token][c]; region ids ----
    {
        const int c  = tid & 127;
        const int rb = tid >> 7;
        const int w0 = ww*8 + 4;
        const int w1 = (ww*8 + 8) & 127;
#pragma unroll
        for (int k = 0; k < 4; ++k) {
            const int r    = k*2 + rb;
            const int srch = (wh*8 + r + 4) & 127;
            const size_t rowbase = (((size_t)(b*128 + c))*128 + srch)*128;
            float va[4], vb[4];
            g_ld4<DT>(x, rowbase + w0, va);
            g_ld4<DT>(x, rowbase + w1, vb);
#pragma unroll
            for (int j = 0; j < 4; ++j) {
                Xs[(r*8 + j)*136 + c]     = (bf16)va[j];
                Xs[(r*8 + 4 + j)*136 + c] = (bf16)vb[j];
            }
        }
        if (tid < 64) {
            const int rr = tid >> 3, cc = tid & 7;
            const int hs_ = wh*8 + rr, wsc = ww*8 + cc;
            const int rh = (hs_ < 120) ? 0 : ((hs_ < 124) ? 1 : 2);
            const int rw = (wsc < 120) ? 0 : ((wsc < 124) ? 1 : 2);
            rid[tid] = rh*3 + rw;
        }
    }
    __syncthreads();

    // ---- stage 1: qkv = Xs @ qkv_w^T + bias; q,k -> qkvs; v -> vs (transposed) ----
    {
        f32x4 acc[4][6];
#pragma unroll
        for (int mt = 0; mt < 4; ++mt)
#pragma unroll
            for (int nl = 0; nl < 6; ++nl) acc[mt][nl] = (f32x4){0.f, 0.f, 0.f, 0.f};
#pragma unroll
        for (int ks = 0; ks < 4; ++ks) {
            bf16x8 a[4];
#pragma unroll
            for (int mt = 0; mt < 4; ++mt)
                a[mt] = *(const bf16x8*)&Xs[(mt*16 + l15)*136 + ks*32 + quad*8];
#pragma unroll
            for (int nl = 0; nl < 6; ++nl) {
                const int o = (wv*6 + nl)*16 + l15;
                bf16x8 bw = *(const bf16x8*)&qkvw[(size_t)o*128 + ks*32 + quad*8];
#pragma unroll
                for (int mt = 0; mt < 4; ++mt)
                    acc[mt][nl] = MFMA16(a[mt], bw, acc[mt][nl]);
            }
        }
#pragma unroll
        for (int nl = 0; nl < 6; ++nl) {
            const int col = (wv*6 + nl)*16 + l15;
            const float bias = qkvb[col];
#pragma unroll
            for (int mt = 0; mt < 4; ++mt)
#pragma unroll
                for (int r = 0; r < 4; ++r) {
                    const int row = mt*16 + quad*4 + r;
                    const float v = acc[mt][nl][r] + bias;
                    if (col < 256) qkvs[row*264 + col] = (bf16)v;       // tile-uniform branch
                    else           vs[(col - 256)*72 + row] = (bf16)v;
                }
        }
    }
    __syncthreads();

    // ---- stage 2: per-head q/k row L2 norms (wave = head, lane = token) ----
    {
        const int n = lane;
        const bf16* qrow = &qkvs[n*264 + wv*32];
        const bf16* krow = &qkvs[n*264 + 128 + wv*32];
        float sq = 0.f, sk = 0.f;
#pragma unroll
        for (int dd = 0; dd < 4; ++dd) {
            bf16x8 vq = *(const bf16x8*)(qrow + dd*8);
            bf16x8 vk = *(const bf16x8*)(krow + dd*8);
#pragma unroll
            for (int e = 0; e < 8; ++e) {
                const float fq = (float)vq[e]; sq += fq*fq;
                const float fk = (float)vk[e]; sk += fk*fk;
            }
        }
        invqs[wv*64 + n] = 1.0f / fmaxf(sqrtf(sq), 1e-12f);
        invks[wv*64 + n] = 1.0f / fmaxf(sqrtf(sk), 1e-12f);
    }
    __syncthreads();

    // ---- stage 3: S = scale*(q.k)*invq*invk + bias + mask; softmax; P -> LDS (over qkvs) ----
    {
        const float scale = scales[wv];
        f32x4 s[4][4];
#pragma unroll
        for (int mt = 0; mt < 4; ++mt)
#pragma unroll
            for (int nt = 0; nt < 4; ++nt) s[mt][nt] = (f32x4){0.f, 0.f, 0.f, 0.f};
        bf16x8 aq[4];
#pragma unroll
        for (int mt = 0; mt < 4; ++mt)
            aq[mt] = *(const bf16x8*)&qkvs[(mt*16 + l15)*264 + wv*32 + quad*8];
#pragma unroll
        for (int nt = 0; nt < 4; ++nt) {
            bf16x8 bk = *(const bf16x8*)&qkvs[(nt*16 + l15)*264 + 128 + wv*32 + quad*8];
#pragma unroll
            for (int mt = 0; mt < 4; ++mt)
                s[mt][nt] = MFMA16(aq[mt], bk, s[mt][nt]);
        }
        __syncthreads();   // all waves done reading q/k before P overlays qkvs
        const float* bg = biasAll + wv*4096;
        const bool bnd = (wh == 15) || (ww == 15);
        float ikj[4]; int rj[4];
#pragma unroll
        for (int nt = 0; nt < 4; ++nt) {
            ikj[nt] = invks[wv*64 + nt*16 + l15];
            rj[nt]  = rid[nt*16 + l15];
        }
#pragma unroll
        for (int mt = 0; mt < 4; ++mt)
#pragma unroll
            for (int r = 0; r < 4; ++r) {
                const int i = mt*16 + quad*4 + r;
                const float iqs = invqs[wv*64 + i] * scale;
                const int ri = rid[i];
#pragma unroll
                for (int nt = 0; nt < 4; ++nt) {
                    const int j = nt*16 + l15;
                    float v = s[mt][nt][r] * (iqs * ikj[nt]) + bg[i*64 + j];
                    if (bnd && (ri != rj[nt])) v -= 100.0f;
                    s[mt][nt][r] = v;
                }
            }
        // softmax over j (16 lanes of the quad x 4 n-tiles)
#pragma unroll
        for (int mt = 0; mt < 4; ++mt) {
            float mx[4], sm[4];
#pragma unroll
            for (int r = 0; r < 4; ++r) {
                float m = fmaxf(fmaxf(s[mt][0][r], s[mt][1][r]), fmaxf(s[mt][2][r], s[mt][3][r]));
                m = fmaxf(m, __shfl_xor(m, 1));
                m = fmaxf(m, __shfl_xor(m, 2));
                m = fmaxf(m, __shfl_xor(m, 4));
                m = fmaxf(m, __shfl_xor(m, 8));
                mx[r] = m; sm[r] = 0.f;
            }
#pragma unroll
            for (int nt = 0; nt < 4; ++nt)
#pragma unroll
                for (int r = 0; r < 4; ++r) {
                    const float e = __expf(s[mt][nt][r] - mx[r]);
                    s[mt][nt][r] = e;
                    sm[r] += e;
                }
#pragma unroll
            for (int r = 0; r < 4; ++r) {
                float t2 = sm[r];
                t2 += __shfl_xor(t2, 1);
                t2 += __shfl_xor(t2, 2);
                t2 += __shfl_xor(t2, 4);
                t2 += __shfl_xor(t2, 8);
                sm[r] = 1.0f / t2;
            }
#pragma unroll
            for (int nt = 0; nt < 4; ++nt)
#pragma unroll
                for (int r = 0; r < 4; ++r) {
                    const float p = s[mt][nt][r] * sm[r];
                    Ps[wv*64*72 + (mt*16 + quad*4 + r)*72 + nt*16 + l15] = (bf16)p;
                }
        }
    }
    __syncthreads();

    // ---- stage 4: O = P @ V -> Os (overlays vs after barrier) ----
    {
        f32x4 o[4][2];
#pragma unroll
        for (int mt = 0; mt < 4; ++mt)
#pragma unroll
            for (int nt = 0; nt < 2; ++nt) o[mt][nt] = (f32x4){0.f, 0.f, 0.f, 0.f};
#pragma unroll
        for (int ks = 0; ks < 2; ++ks) {
            bf16x8 ap[4];
#pragma unroll
            for (int mt = 0; mt < 4; ++mt)
                ap[mt] = *(const bf16x8*)&Ps[wv*64*72 + (mt*16 + l15)*72 + ks*32 + quad*8];
#pragma unroll
            for (int nt = 0; nt < 2; ++nt) {
                bf16x8 bv = *(const bf16x8*)&vs[(wv*32 + nt*16 + l15)*72 + ks*32 + quad*8];
#pragma unroll
                for (int mt = 0; mt < 4; ++mt)
                    o[mt][nt] = MFMA16(ap[mt], bv, o[mt][nt]);
            }
        }
        __syncthreads();   // all waves done reading vs before Os overlays it
#pragma unroll
        for (int mt = 0; mt < 4; ++mt)
#pragma unroll
            for (int nt = 0; nt < 2; ++nt)
#pragma unroll
                for (int r = 0; r < 4; ++r) {
                    const int i = mt*16 + quad*4 + r;
                    Os[i*136 + wv*32 + nt*16 + l15] = (bf16)o[mt][nt][r];
                }
    }
    __syncthreads();

    // ---- stage 5: proj (waves own 32 output cols) + LN1 + residual -> x1s (overlays qkvs/Ps) ----
    {
        f32x4 pa[4][2];
#pragma unroll
        for (int mt = 0; mt < 4; ++mt)
#pragma unroll
            for (int nt = 0; nt < 2; ++nt) pa[mt][nt] = (f32x4){0.f, 0.f, 0.f, 0.f};
#pragma unroll
        for (int ks = 0; ks < 4; ++ks) {
            bf16x8 ao[4];
#pragma unroll
            for (int mt = 0; mt < 4; ++mt)
                ao[mt] = *(const bf16x8*)&Os[(mt*16 + l15)*136 + ks*32 + quad*8];
#pragma unroll
            for (int nt = 0; nt < 2; ++nt) {
                const int oc = wv*32 + nt*16 + l15;
                bf16x8 bw = *(const bf16x8*)&projw[(size_t)oc*128 + ks*32 + quad*8];
#pragma unroll
                for (int mt = 0; mt < 4; ++mt)
                    pa[mt][nt] = MFMA16(ao[mt], bw, pa[mt][nt]);
            }
        }
        float pb[2], wn[2], bn[2];
#pragma unroll
        for (int nt = 0; nt < 2; ++nt) {
            const int oc = wv*32 + nt*16 + l15;
            pb[nt] = projb[oc]; wn[nt] = n1wf[oc]; bn[nt] = n1bf[oc];
        }
        // pass 1: per-wave partial sums over its 32 cols
#pragma unroll
        for (int mt = 0; mt < 4; ++mt)
#pragma unroll
            for (int r = 0; r < 4; ++r) {
                pa[mt][0][r] += pb[0];
                pa[mt][1][r] += pb[1];
                float sv = pa[mt][0][r] + pa[mt][1][r];
                sv += __shfl_xor(sv, 1); sv += __shfl_xor(sv, 2);
                sv += __shfl_xor(sv, 4); sv += __shfl_xor(sv, 8);
                if (l15 == 0) psum[wv*64 + mt*16 + quad*4 + r] = sv;
            }
        __syncthreads();
        float mu[4][4];
#pragma unroll
        for (int mt = 0; mt < 4; ++mt)
#pragma unroll
            for (int r = 0; r < 4; ++r) {
                const int i = mt*16 + quad*4 + r;
                mu[mt][r] = (psum[i] + psum[64+i] + psum[128+i] + psum[192+i]) * (1.0f/128.0f);
                const float d0 = pa[mt][0][r] - mu[mt][r];
                const float d1 = pa[mt][1][r] - mu[mt][r];
                float sv = d0*d0 + d1*d1;
                sv += __shfl_xor(sv, 1); sv += __shfl_xor(sv, 2);
                sv += __shfl_xor(sv, 4); sv += __shfl_xor(sv, 8);
                if (l15 == 0) pvar[wv*64 + i] = sv;
            }
        __syncthreads();
#pragma unroll
        for (int mt = 0; mt < 4; ++mt)
#pragma unroll
            for (int r = 0; r < 4; ++r) {
                const int i = mt*16 + quad*4 + r;
                const float var = (pvar[i] + pvar[64+i] + pvar[128+i] + pvar[192+i]) * (1.0f/128.0f);
                const float rstd = rsqrtf(var + 1e-5f);
#pragma unroll
                for (int nt = 0; nt < 2; ++nt) {
                    const int oc = wv*32 + nt*16 + l15;
                    const float y = (pa[mt][nt][r] - mu[mt][r]) * rstd * wn[nt] + bn[nt];
                    const float x1v = bf2f(Xs[i*136 + oc]) + y;
                    x1s[i*136 + oc] = (bf16)x1v;     // x1s overlays qkvs/Ps (dead)
                }
            }
    }
    __syncthreads();

    // ---- stage 6: MLP fc1+silu+fc2 on the x1 tile already in LDS; hidden chunked 4x128 ----
    f32x4 ya[4][2];
#pragma unroll
    for (int mt = 0; mt < 4; ++mt)
#pragma unroll
        for (int nt = 0; nt < 2; ++nt) ya[mt][nt] = (f32x4){0.f, 0.f, 0.f, 0.f};

#pragma unroll
    for (int ch = 0; ch < 4; ++ch) {
        if (ch) __syncthreads();   // previous chunk's fc2 reads of hs must finish
        // fc1 chunk: 64 tokens x 128 hidden (wave owns 32 hidden cols)
        f32x4 ha[4][2];
#pragma unroll
        for (int mt = 0; mt < 4; ++mt)
#pragma unroll
            for (int nt = 0; nt < 2; ++nt) ha[mt][nt] = (f32x4){0.f, 0.f, 0.f, 0.f};
#pragma unroll
        for (int ks = 0; ks < 4; ++ks) {
            bf16x8 a[4];
#pragma unroll
            for (int mt = 0; mt < 4; ++mt)
                a[mt] = *(const bf16x8*)&x1s[(mt*16 + l15)*136 + ks*32 + quad*8];
#pragma unroll
            for (int nt = 0; nt < 2; ++nt) {
                const int hid = ch*128 + wv*32 + nt*16 + l15;
                bf16x8 bw = *(const bf16x8*)&fc1w[(size_t)hid*128 + ks*32 + quad*8];
#pragma unroll
                for (int mt = 0; mt < 4; ++mt)
                    ha[mt][nt] = MFMA16(a[mt], bw, ha[mt][nt]);
            }
        }
#pragma unroll
        for (int nt = 0; nt < 2; ++nt) {
            const int hid = ch*128 + wv*32 + nt*16 + l15;
            const float bb = fc1bf[hid];
            const int hl = wv*32 + nt*16 + l15;
#pragma unroll
            for (int mt = 0; mt < 4; ++mt)
#pragma unroll
                for (int r = 0; r < 4; ++r) {
                    float v = ha[mt][nt][r] + bb;
                    v = v / (1.0f + __expf(-v));   // silu
                    hs[(mt*16 + quad*4 + r)*136 + hl] = (bf16)v;
                }
        }
        __syncthreads();
        // fc2 partial: wave owns 32 OUTPUT cols, all 64 tokens
#pragma unroll
        for (int ks = 0; ks < 4; ++ks) {
            bf16x8 ah[4];
#pragma unroll
            for (int mt = 0; mt < 4; ++mt)
                ah[mt] = *(const bf16x8*)&hs[(mt*16 + l15)*136 + ks*32 + quad*8];
#pragma unroll
            for (int nt = 0; nt < 2; ++nt) {
                const int oc = wv*32 + nt*16 + l15;
                bf16x8 bw = *(const bf16x8*)&fc2w[(size_t)oc*512 + ch*128 + ks*32 + quad*8];
#pragma unroll
                for (int mt = 0; mt < 4; ++mt)
                    ya[mt][nt] = MFMA16(ah[mt], bw, ya[mt][nt]);
            }
        }
    }
    __syncthreads();   // all fc2 reads of hs done before reuse as x2 staging

    // ---- stage 7: bias + LN2 + residual(x1s) -> x2s (overlays hs) ----
    {
        float pb[2], wn[2], bn[2];
#pragma unroll
        for (int nt = 0; nt < 2; ++nt) {
            const int oc = wv*32 + nt*16 + l15;
            pb[nt] = fc2bf[oc]; wn[nt] = n2wf[oc]; bn[nt] = n2bf[oc];
        }
#pragma unroll
        for (int mt = 0; mt < 4; ++mt)
#pragma unroll
            for (int r = 0; r < 4; ++r) {
                ya[mt][0][r] += pb[0];
                ya[mt][1][r] += pb[1];
                float sv = ya[mt][0][r] + ya[mt][1][r];
                sv += __shfl_xor(sv, 1); sv += __shfl_xor(sv, 2);
                sv += __shfl_xor(sv, 4); sv += __shfl_xor(sv, 8);
                if (l15 == 0) psum[wv*64 + mt*16 + quad*4 + r] = sv;
            }
        __syncthreads();
        float mu[4][4];
#pragma unroll
        for (int mt = 0; mt < 4; ++mt)
#pragma unroll
            for (int r = 0; r < 4; ++r) {
                const int i = mt*16 + quad*4 + r;
                mu[mt][r] = (psum[i] + psum[64+i] + psum[128+i] + psum[192+i]) * (1.0f/128.0f);
                const float d0 = ya[mt][0][r] - mu[mt][r];
                const float d1 = ya[mt][1][r] - mu[mt][r];
                float sv = d0*d0 + d1*d1;
                sv += __shfl_xor(sv, 1); sv += __shfl_xor(sv, 2);
                sv += __shfl_xor(sv, 4); sv += __shfl_xor(sv, 8);
                if (l15 == 0) pvar[wv*64 + i] = sv;
            }
        __syncthreads();
        bf16* x2s = hs;
#pragma unroll
        for (int mt = 0; mt < 4; ++mt)
#pragma unroll
            for (int r = 0; r < 4; ++r) {
                const int i = mt*16 + quad*4 + r;
                const float var = (pvar[i] + pvar[64+i] + pvar[128+i] + pvar[192+i]) * (1.0f/128.0f);
                const float rstd = rsqrtf(var + 1e-5f);
#pragma unroll
                for (int nt = 0; nt < 2; ++nt) {
                    const int oc = wv*32 + nt*16 + l15;
                    const float yv = (ya[mt][nt][r] - mu[mt][r]) * rstd * wn[nt] + bn[nt];
                    const float x2v = bf2f(x1s[i*136 + oc]) + yv;
                    x2s[i*136 + oc] = (bf16)x2v;
                }
            }
    }
    __syncthreads();

    // ---- stage 8: write x2 to planar (B, C, H, W) at reverse-shifted positions ----
    {
        const bf16* x2s = hs;
        const int wf0 = ww*8 + 4;
        const int wf1 = (ww*8 + 8) & 127;
#pragma unroll
        for (int g = 0; g < 4; ++g) {
            const int idx = g*256 + tid;          // 0..1023 = (rr, c)
            const int c  = idx & 127;             // lane-consecutive c -> conflict-free LDS reads
            const int rr = idx >> 7;              // covers 0..7 over the 4 iterations x 2 halves
            const int hf = (wh*8 + rr + 4) & 127;
            const size_t rowb = ((size_t)(b*128 + c))*16384 + (size_t)hf*128;
            if constexpr (DT == 0) {
                const unsigned short* xu = (const unsigned short*)x2s;
                uint2 u0, u1;
                u0.x = (unsigned)xu[(rr*8+0)*136 + c] | ((unsigned)xu[(rr*8+1)*136 + c] << 16);
                u0.y = (unsigned)xu[(rr*8+2)*136 + c] | ((unsigned)xu[(rr*8+3)*136 + c] << 16);
                u1.x = (unsigned)xu[(rr*8+4)*136 + c] | ((unsigned)xu[(rr*8+5)*136 + c] << 16);
                u1.y = (unsigned)xu[(rr*8+6)*136 + c] | ((unsigned)xu[(rr*8+7)*136 + c] << 16);
                bf16* dstb = (bf16*)out;
                *(uint2*)(dstb + rowb + wf0) = u0;
                *(uint2*)(dstb + rowb + wf1) = u1;
            } else {
                float4 u0, u1;
                u0.x = bf2f(x2s[(rr*8+0)*136 + c]); u0.y = bf2f(x2s[(rr*8+1)*136 + c]);
                u0.z = bf2f(x2s[(rr*8+2)*136 + c]); u0.w = bf2f(x2s[(rr*8+3)*136 + c]);
                u1.x = bf2f(x2s[(rr*8+4)*136 + c]); u1.y = bf2f(x2s[(rr*8+5)*136 + c]);
                u1.z = bf2f(x2s[(rr*8+6)*136 + c]); u1.w = bf2f(x2s[(rr*8+7)*136 + c]);
                float* dstf = (float*)out;
                *(float4*)(dstf + rowb + wf0) = u0;
                *(float4*)(dstf + rowb + wf1) = u1;
            }
        }
    }
}

extern "C" void kernel_launch(void* const* d_in, const int* in_sizes, int n_in,
                              void* d_out, int out_size, void* d_ws, size_t ws_size,
                              hipStream_t stream)
{
    (void)in_sizes; (void)n_in; (void)out_size; (void)ws_size;
    const void* x      = d_in[0];
    const void* n1w    = d_in[1];
    const void* n1b    = d_in[2];
    const void* qkv_w  = d_in[3];
    const void* q_bias = d_in[4];
    const void* v_bias = d_in[5];
    const void* lscale = d_in[6];
    const void* cpb_w1 = d_in[7];
    const void* cpb_b1 = d_in[8];
    const void* cpb_w2 = d_in[9];
    const void* proj_w = d_in[10];
    const void* proj_b = d_in[11];
    const void* n2w    = d_in[12];
    const void* n2b    = d_in[13];
    const void* fc1w   = d_in[14];
    const void* fc1b   = d_in[15];
    const void* fc2w   = d_in[16];
    const void* fc2b   = d_in[17];

    char*  ws      = (char*)d_ws;
    float* biasAll = (float*)ws;                      // 64 KiB @ 0
    float* scales  = (float*)(ws + OFF_SCALES);
    int*   flag    = (int*)(ws + OFF_FLAG);

    k_precompute<<<dim3(1), dim3(256), 0, stream>>>(cpb_w1, cpb_b1, cpb_w2, lscale, qkv_w,
                                                    biasAll, scales, flag);
    k_convert<<<dim3(96), dim3(256), 0, stream>>>(qkv_w, proj_w, fc1w, fc2w,
                                                  q_bias, v_bias, proj_b, n1w, n1b,
                                                  fc1b, fc2b, n2w, n2b, flag, ws);
    k_fused<0><<<dim3(4096), dim3(256), 0, stream>>>(x,
        (const bf16*)(ws + OFF_QKVW), (const float*)(ws + OFF_QKVB),
        (const bf16*)(ws + OFF_PROJW), (const float*)(ws + OFF_PROJB),
        (const float*)(ws + OFF_N1W), (const float*)(ws + OFF_N1B),
        (const bf16*)(ws + OFF_FC1W), (const float*)(ws + OFF_FC1B),
        (const bf16*)(ws + OFF_FC2W), (const float*)(ws + OFF_FC2B),
        (const float*)(ws + OFF_N2W), (const float*)(ws + OFF_N2B),
        biasAll, scales, flag, d_out);
    k_fused<1><<<dim3(4096), dim3(256), 0, stream>>>(x,
        (const bf16*)(ws + OFF_QKVW), (const float*)(ws + OFF_QKVB),
        (const bf16*)(ws + OFF_PROJW), (const float*)(ws + OFF_PROJB),
        (const float*)(ws + OFF_N1W), (const float*)(ws + OFF_N1B),
        (const bf16*)(ws + OFF_FC1W), (const float*)(ws + OFF_FC1B),
        (const bf16*)(ws + OFF_FC2W), (const float*)(ws + OFF_FC2B),
        (const float*)(ws + OFF_N2W), (const float*)(ws + OFF_N2B),
        biasAll, scales, flag, d_out);
}

// Round 3
// 588.153 us; speedup vs baseline: 2.4253x; 1.1925x over previous
//
#include <hip/hip_runtime.h>
#include <cstdint>
#include <cstddef>

typedef __bf16 bf16;
typedef __bf16 bf16x4 __attribute__((ext_vector_type(4)));
typedef __bf16 bf16x8 __attribute__((ext_vector_type(8)));
typedef float f32x4 __attribute__((ext_vector_type(4)));

#define MFMA16(a, b, c) __builtin_amdgcn_mfma_f32_16x16x32_bf16((a), (b), (c), 0, 0, 0)

__device__ __forceinline__ float bf2f(bf16 v) { return (float)v; }

__device__ __forceinline__ void pack4(float a0, float a1, float a2, float a3, bf16* dst) {
    bf16x4 v; v[0] = (bf16)a0; v[1] = (bf16)a1; v[2] = (bf16)a2; v[3] = (bf16)a3;
    *(bf16x4*)dst = v;
}

// ---- workspace layout (bytes) ----
#define OFF_SCALES 65536
#define OFF_FLAG   65552
#define OFF_QKVB   65600
#define OFF_PROJB  67136
#define OFF_N1W    67648
#define OFF_N1B    68160
#define OFF_FC1B   68672
#define OFF_FC2B   70720
#define OFF_N2W    71232
#define OFF_N2B    71744
#define OFF_QKVW   73728
#define OFF_PROJW  172032
#define OFF_FC1W   204800
#define OFF_FC2W   335872

// ---- dtype-adaptive global load helper for the big input tensor only ----
template<int DT>
__device__ __forceinline__ void g_ld4(const void* base, size_t idx, float* o) {
    if constexpr (DT == 0) {
        uint2 d = *(const uint2*)((const bf16*)base + idx);
        const bf16* p = (const bf16*)&d;
        o[0] = bf2f(p[0]); o[1] = bf2f(p[1]); o[2] = bf2f(p[2]); o[3] = bf2f(p[3]);
    } else {
        float4 d = *(const float4*)((const float*)base + idx);
        o[0] = d.x; o[1] = d.y; o[2] = d.z; o[3] = d.w;
    }
}

// ---------------- kernel 0: init = dtype detect + CPB table (block 0) + weight convert (blocks 1..96) ----------------
__global__ void k_init(const void* __restrict__ cpb_w1, const void* __restrict__ cpb_b1,
                       const void* __restrict__ cpb_w2, const void* __restrict__ logit_scale,
                       const void* __restrict__ qkv_w, const void* __restrict__ proj_w,
                       const void* __restrict__ fc1w, const void* __restrict__ fc2w,
                       const void* __restrict__ q_bias, const void* __restrict__ v_bias,
                       const void* __restrict__ proj_b, const void* __restrict__ n1w, const void* __restrict__ n1b,
                       const void* __restrict__ fc1b, const void* __restrict__ fc2b,
                       const void* __restrict__ n2w, const void* __restrict__ n2b,
                       char* __restrict__ ws)
{
    const int t = threadIdx.x;
    __shared__ int s_cnt;
    if (t == 0) s_cnt = 0;
    __syncthreads();
    {   // per-block dtype detection: fp32-viewed-as-u16 has ~40% wild exponents
        const unsigned short* u = (const unsigned short*)qkv_w;
        int c = 0;
        for (int i = t; i < 1024; i += 256) {
            const int e = (u[i] >> 7) & 0xFF;
            if (e >= 0x90 || (e != 0 && e <= 0x60)) ++c;
        }
        atomicAdd(&s_cnt, c);
    }
    __syncthreads();
    const int isf = (s_cnt > 64) ? 1 : 0;

    if (blockIdx.x == 0) {
        // ---- CPB bias table + logit scales + flag ----
        float* biasAll = (float*)ws;
        float* scales  = (float*)(ws + OFF_SCALES);
        int*   flag    = (int*)(ws + OFF_FLAG);
        if (t == 0) *flag = isf;
        __shared__ float w1s[1024];
        __shared__ float b1s[512];
        __shared__ float w2s[2048];
        __shared__ float tabv[225][4];
        if (isf) {
            const float* w1 = (const float*)cpb_w1;
            const float* b1 = (const float*)cpb_b1;
            const float* w2 = (const float*)cpb_w2;
            for (int i = t; i < 1024; i += 256) w1s[i] = w1[i];
            for (int i = t; i < 512;  i += 256) b1s[i] = b1[i];
            for (int i = t; i < 2048; i += 256) w2s[i] = w2[i];
            if (t < 4) scales[t] = expf(fminf(((const float*)logit_scale)[t], 4.6051701859880914f));
        } else {
            const bf16* w1 = (const bf16*)cpb_w1;
            const bf16* b1 = (const bf16*)cpb_b1;
            const bf16* w2 = (const bf16*)cpb_w2;
            for (int i = t; i < 1024; i += 256) w1s[i] = bf2f(w1[i]);
            for (int i = t; i < 512;  i += 256) b1s[i] = bf2f(b1[i]);
            for (int i = t; i < 2048; i += 256) w2s[i] = bf2f(w2[i]);
            if (t < 4) scales[t] = expf(fminf(bf2f(((const bf16*)logit_scale)[t]), 4.6051701859880914f));
        }
        __syncthreads();
        if (t < 225) {
            const int i = t / 15, j = t % 15;
            auto relf = [](int tt) -> float {
                float tf = (float)tt * (8.0f / 7.0f);
                float a = log2f(fabsf(tf) + 1.0f) * (1.0f / 3.0f);
                return tt < 0 ? -a : a;
            };
            const float x0 = relf(i - 7), x1 = relf(j - 7);
            float a0 = 0.f, a1 = 0.f, a2 = 0.f, a3 = 0.f;
            for (int jj = 0; jj < 512; ++jj) {
                float hv = w1s[jj*2] * x0 + w1s[jj*2+1] * x1 + b1s[jj];
                hv = fmaxf(hv, 0.0f);
                a0 += w2s[jj]        * hv;
                a1 += w2s[512 + jj]  * hv;
                a2 += w2s[1024 + jj] * hv;
                a3 += w2s[1536 + jj] * hv;
            }
            tabv[t][0] = a0; tabv[t][1] = a1; tabv[t][2] = a2; tabv[t][3] = a3;
        }
        __syncthreads();
        for (int idx = t; idx < 4*64*64; idx += 256) {
            const int h = idx >> 12, rem = idx & 4095, i = rem >> 6, j = rem & 63;
            const int di = (i >> 3) - (j >> 3) + 7;
            const int dj = (i & 7) - (j & 7) + 7;
            const float bv = tabv[di*15 + dj][h];
            biasAll[idx] = 16.0f / (1.0f + expf(-bv));
        }
    } else {
        // ---- weight/bias conversion ----
        const int g  = (blockIdx.x - 1) * 256 + t;
        const int gs = 96 * 256;
        bf16* qw = (bf16*)(ws + OFF_QKVW);
        bf16* pw = (bf16*)(ws + OFF_PROJW);
        bf16* f1 = (bf16*)(ws + OFF_FC1W);
        bf16* f2 = (bf16*)(ws + OFF_FC2W);
        if (isf) {
            const float* a = (const float*)qkv_w;  for (int i = g; i < 49152; i += gs) qw[i] = (bf16)a[i];
            const float* b = (const float*)proj_w; for (int i = g; i < 16384; i += gs) pw[i] = (bf16)b[i];
            const float* c = (const float*)fc1w;   for (int i = g; i < 65536; i += gs) f1[i] = (bf16)c[i];
            const float* d = (const float*)fc2w;   for (int i = g; i < 65536; i += gs) f2[i] = (bf16)d[i];
        } else {
            const bf16* a = (const bf16*)qkv_w;  for (int i = g; i < 49152; i += gs) qw[i] = a[i];
            const bf16* b = (const bf16*)proj_w; for (int i = g; i < 16384; i += gs) pw[i] = b[i];
            const bf16* c = (const bf16*)fc1w;   for (int i = g; i < 65536; i += gs) f1[i] = c[i];
            const bf16* d = (const bf16*)fc2w;   for (int i = g; i < 65536; i += gs) f2[i] = d[i];
        }
        auto ldf = [&](const void* p, int i) -> float {
            return isf ? ((const float*)p)[i] : bf2f(((const bf16*)p)[i]);
        };
        float* qb  = (float*)(ws + OFF_QKVB);
        float* pb  = (float*)(ws + OFF_PROJB);
        float* w1  = (float*)(ws + OFF_N1W);
        float* b1  = (float*)(ws + OFF_N1B);
        float* f1b = (float*)(ws + OFF_FC1B);
        float* f2b = (float*)(ws + OFF_FC2B);
        float* w2  = (float*)(ws + OFF_N2W);
        float* b2  = (float*)(ws + OFF_N2B);
        for (int i = g; i < 384; i += gs)
            qb[i] = (i < 128) ? ldf(q_bias, i) : ((i < 256) ? 0.0f : ldf(v_bias, i - 256));
        for (int i = g; i < 512; i += gs) f1b[i] = ldf(fc1b, i);
        for (int i = g; i < 128; i += gs) {
            pb[i]  = ldf(proj_b, i); w1[i] = ldf(n1w, i); b1[i] = ldf(n1b, i);
            f2b[i] = ldf(fc2b, i);   w2[i] = ldf(n2w, i); b2[i] = ldf(n2b, i);
        }
    }
}

// ---------------- kernel 1: FULLY FUSED layer, swapped-operand MFMAs (packed epilogues) ----------------
// one block per (batch, window): 4096 blocks, 256 threads (wave = head for attn)
__global__ __launch_bounds__(256, 2) void k_fused(
    const void* __restrict__ x,
    const bf16* __restrict__ qkvw, const float* __restrict__ qkvb,
    const bf16* __restrict__ projw, const float* __restrict__ projb,
    const float* __restrict__ n1wf, const float* __restrict__ n1bf,
    const bf16* __restrict__ fc1w, const float* __restrict__ fc1bf,
    const bf16* __restrict__ fc2w, const float* __restrict__ fc2bf,
    const float* __restrict__ n2wf, const float* __restrict__ n2bf,
    const float* __restrict__ biasAll, const float* __restrict__ scales,
    const int* __restrict__ flag, void* __restrict__ out)
{
    const int isf = *flag;

    __shared__ __align__(16) char smem[75008];
    bf16* Xs    = (bf16*)smem;                   // [64][136] window input / residual
    bf16* qkvs  = (bf16*)(smem + 17408);         // [64][264] q|k ; reuse: PsT[4][64][72] ; x1s[64][136]
    bf16* PsT   = qkvs;                          // per-head P^T stored row-major [i][j]
    bf16* x1s   = qkvs;
    bf16* vs    = (bf16*)(smem + 54272);         // [128][72] v^T ; reuse: Os[64][136] ; hs[64][136] ; x2s
    bf16* Os    = vs;
    bf16* hs    = vs;
    float* invqs = (float*)(smem + 72704);       // 256 ; reuse: LN partial sums (psum)
    float* invks = (float*)(smem + 73728);       // 256 ; reuse: LN partial sq-dev (pvar)
    int*   rid   = (int*)(smem + 74752);         // 64
    float* psum = invqs;
    float* pvar = invks;

    const int tid  = threadIdx.x;
    const int wv   = tid >> 6;
    const int lane = tid & 63;
    const int l15  = lane & 15;
    const int quad = lane >> 4;

    // XCD-aware bijective swizzle
    const int bid0 = blockIdx.x;
    const int bid  = ((bid0 & 7) << 9) | (bid0 >> 3);
    const int b   = bid >> 8;
    const int wh  = (bid >> 4) & 15;
    const int ww  = bid & 15;

    // ---- stage 0: gather shifted window into Xs[token][c]; region ids ----
    {
        const int c  = tid & 127;
        const int rb = tid >> 7;
        const int w0 = ww*8 + 4;
        const int w1 = (ww*8 + 8) & 127;
#pragma unroll
        for (int k = 0; k < 4; ++k) {
            const int r    = k*2 + rb;
            const int srch = (wh*8 + r + 4) & 127;
            const size_t rowbase = (((size_t)(b*128 + c))*128 + srch)*128;
            float va[4], vb[4];
            if (isf) { g_ld4<1>(x, rowbase + w0, va); g_ld4<1>(x, rowbase + w1, vb); }
            else     { g_ld4<0>(x, rowbase + w0, va); g_ld4<0>(x, rowbase + w1, vb); }
#pragma unroll
            for (int j = 0; j < 4; ++j) {
                Xs[(r*8 + j)*136 + c]     = (bf16)va[j];
                Xs[(r*8 + 4 + j)*136 + c] = (bf16)vb[j];
            }
        }
        if (tid < 64) {
            const int rr = tid >> 3, cc = tid & 7;
            const int hs_ = wh*8 + rr, wsc = ww*8 + cc;
            const int rh = (hs_ < 120) ? 0 : ((hs_ < 124) ? 1 : 2);
            const int rw = (wsc < 120) ? 0 : ((wsc < 124) ? 1 : 2);
            rid[tid] = rh*3 + rw;
        }
    }
    __syncthreads();

    // ---- stage 1: qkv = X @ W^T + bias. q/k tiles: swapped MFMA -> packed row-major store.
    //      v tiles: normal MFMA -> packed transposed store into vs[c][token]. ----
    {
        f32x4 acc[6][4];
#pragma unroll
        for (int nl = 0; nl < 6; ++nl)
#pragma unroll
            for (int mt = 0; mt < 4; ++mt) acc[nl][mt] = (f32x4){0.f, 0.f, 0.f, 0.f};
#pragma unroll
        for (int ks = 0; ks < 4; ++ks) {
            bf16x8 a[4];
#pragma unroll
            for (int mt = 0; mt < 4; ++mt)
                a[mt] = *(const bf16x8*)&Xs[(mt*16 + l15)*136 + ks*32 + quad*8];
#pragma unroll
            for (int nl = 0; nl < 6; ++nl) {
                const int tile = wv*6 + nl;
                bf16x8 bw = *(const bf16x8*)&qkvw[(size_t)(tile*16 + l15)*128 + ks*32 + quad*8];
                if (tile < 16) {   // q/k: C^T = W x X
#pragma unroll
                    for (int mt = 0; mt < 4; ++mt)
                        acc[nl][mt] = MFMA16(bw, a[mt], acc[nl][mt]);
                } else {           // v: C = X x W
#pragma unroll
                    for (int mt = 0; mt < 4; ++mt)
                        acc[nl][mt] = MFMA16(a[mt], bw, acc[nl][mt]);
                }
            }
        }
#pragma unroll
        for (int nl = 0; nl < 6; ++nl) {
            const int tile = wv*6 + nl;
            const int ctb  = tile*16;
            if (ctb < 256) {
                // lane holds cols ctb+quad*4..+3 for token mt*16+l15
                const float4 qb4 = *(const float4*)&qkvb[ctb + quad*4];
#pragma unroll
                for (int mt = 0; mt < 4; ++mt)
                    pack4(acc[nl][mt][0] + qb4.x, acc[nl][mt][1] + qb4.y,
                          acc[nl][mt][2] + qb4.z, acc[nl][mt][3] + qb4.w,
                          &qkvs[(mt*16 + l15)*264 + ctb + quad*4]);
            } else {
                // lane holds tokens mt*16+quad*4..+3 for col ctb+l15
                const float bb = qkvb[ctb + l15];
#pragma unroll
                for (int mt = 0; mt < 4; ++mt)
                    pack4(acc[nl][mt][0] + bb, acc[nl][mt][1] + bb,
                          acc[nl][mt][2] + bb, acc[nl][mt][3] + bb,
                          &vs[(ctb - 256 + l15)*72 + mt*16 + quad*4]);
            }
        }
    }
    __syncthreads();

    // ---- stage 2: per-head q/k row L2 norms (wave = head, lane = token) ----
    {
        const int n = lane;
        const bf16* qrow = &qkvs[n*264 + wv*32];
        const bf16* krow = &qkvs[n*264 + 128 + wv*32];
        float sq = 0.f, sk = 0.f;
#pragma unroll
        for (int dd = 0; dd < 4; ++dd) {
            bf16x8 vq = *(const bf16x8*)(qrow + dd*8);
            bf16x8 vk = *(const bf16x8*)(krow + dd*8);
#pragma unroll
            for (int e = 0; e < 8; ++e) {
                const float fq = (float)vq[e]; sq += fq*fq;
                const float fk = (float)vk[e]; sk += fk*fk;
            }
        }
        invqs[wv*64 + n] = 1.0f / fmaxf(sqrtf(sq), 1e-12f);
        invks[wv*64 + n] = 1.0f / fmaxf(sqrtf(sk), 1e-12f);
    }
    __syncthreads();

    // ---- stage 3: S^T = K x Q^T (swapped); scale+bias+mask; softmax over j; P^T -> PsT ----
    {
        const float scale = scales[wv];
        f32x4 s[4][4];   // [jt][it]: j = jt*16+quad*4+r, i = it*16+l15
#pragma unroll
        for (int jt = 0; jt < 4; ++jt)
#pragma unroll
            for (int it = 0; it < 4; ++it) s[jt][it] = (f32x4){0.f, 0.f, 0.f, 0.f};
        bf16x8 aq[4];
#pragma unroll
        for (int it = 0; it < 4; ++it)
            aq[it] = *(const bf16x8*)&qkvs[(it*16 + l15)*264 + wv*32 + quad*8];
#pragma unroll
        for (int jt = 0; jt < 4; ++jt) {
            bf16x8 bk = *(const bf16x8*)&qkvs[(jt*16 + l15)*264 + 128 + wv*32 + quad*8];
#pragma unroll
            for (int it = 0; it < 4; ++it)
                s[jt][it] = MFMA16(bk, aq[it], s[jt][it]);
        }
        __syncthreads();   // q/k reads done before PsT overlays qkvs

        const float* bg = biasAll + wv*4096;
        const bool bnd = (wh == 15) || (ww == 15);
        float iqs[4]; int ri[4];
#pragma unroll
        for (int it = 0; it < 4; ++it) {
            iqs[it] = invqs[wv*64 + it*16 + l15] * scale;
            ri[it]  = rid[it*16 + l15];
        }
        float4 ikj[4]; int4 rj4[4];
#pragma unroll
        for (int jt = 0; jt < 4; ++jt) {
            ikj[jt] = *(const float4*)&invks[wv*64 + jt*16 + quad*4];
            rj4[jt] = *(const int4*)&rid[jt*16 + quad*4];
        }
#pragma unroll
        for (int it = 0; it < 4; ++it) {
            const int i = it*16 + l15;
#pragma unroll
            for (int jt = 0; jt < 4; ++jt) {
                const float4 bb = *(const float4*)&bg[i*64 + jt*16 + quad*4];
#pragma unroll
                for (int r = 0; r < 4; ++r) {
                    float v = s[jt][it][r] * (iqs[it] * ((const float*)&ikj[jt])[r]) + ((const float*)&bb)[r];
                    if (bnd && (ri[it] != ((const int*)&rj4[jt])[r])) v -= 100.0f;
                    s[jt][it][r] = v;
                }
            }
            // softmax over j for this it: 16 in-lane values + quad-reduce (xor 16, 32)
            float m = s[0][it][0];
#pragma unroll
            for (int jt = 0; jt < 4; ++jt)
#pragma unroll
                for (int r = 0; r < 4; ++r) m = fmaxf(m, s[jt][it][r]);
            m = fmaxf(m, __shfl_xor(m, 16));
            m = fmaxf(m, __shfl_xor(m, 32));
            float sm = 0.f;
#pragma unroll
            for (int jt = 0; jt < 4; ++jt)
#pragma unroll
                for (int r = 0; r < 4; ++r) {
                    const float e = __expf(s[jt][it][r] - m);
                    s[jt][it][r] = e;
                    sm += e;
                }
            sm += __shfl_xor(sm, 16);
            sm += __shfl_xor(sm, 32);
            const float inv = 1.0f / sm;
#pragma unroll
            for (int jt = 0; jt < 4; ++jt)
                pack4(s[jt][it][0]*inv, s[jt][it][1]*inv, s[jt][it][2]*inv, s[jt][it][3]*inv,
                      &PsT[wv*4608 + i*72 + jt*16 + quad*4]);
        }
    }
    __syncthreads();

    // ---- stage 4: O^T = V^T x P^T -> packed row-major Os[token][ch] (overlays vs after barrier) ----
    {
        f32x4 o[2][4];   // [dt][it]: ch = wv*32+dt*16+quad*4+r, token = it*16+l15
#pragma unroll
        for (int dt = 0; dt < 2; ++dt)
#pragma unroll
            for (int it = 0; it < 4; ++it) o[dt][it] = (f32x4){0.f, 0.f, 0.f, 0.f};
#pragma unroll
        for (int ks = 0; ks < 2; ++ks) {
            bf16x8 bp[4];
#pragma unroll
            for (int it = 0; it < 4; ++it)
                bp[it] = *(const bf16x8*)&PsT[wv*4608 + (it*16 + l15)*72 + ks*32 + quad*8];
#pragma unroll
            for (int dt = 0; dt < 2; ++dt) {
                bf16x8 av = *(const bf16x8*)&vs[(wv*32 + dt*16 + l15)*72 + ks*32 + quad*8];
#pragma unroll
                for (int it = 0; it < 4; ++it)
                    o[dt][it] = MFMA16(av, bp[it], o[dt][it]);
            }
        }
        __syncthreads();   // all vs/PsT reads done before Os overlays vs
#pragma unroll
        for (int dt = 0; dt < 2; ++dt)
#pragma unroll
            for (int it = 0; it < 4; ++it)
                pack4(o[dt][it][0], o[dt][it][1], o[dt][it][2], o[dt][it][3],
                      &Os[(it*16 + l15)*136 + wv*32 + dt*16 + quad*4]);
    }
    __syncthreads();

    // ---- stage 5: X1^T = projW x O^T (swapped) + LN1 + residual -> packed x1s ----
    {
        f32x4 pa[2][4];  // [ct][tt]: oc = wv*32+ct*16+quad*4+r, token = tt*16+l15
#pragma unroll
        for (int ct = 0; ct < 2; ++ct)
#pragma unroll
            for (int tt = 0; tt < 4; ++tt) pa[ct][tt] = (f32x4){0.f, 0.f, 0.f, 0.f};
#pragma unroll
        for (int ks = 0; ks < 4; ++ks) {
            bf16x8 bo[4];
#pragma unroll
            for (int tt = 0; tt < 4; ++tt)
                bo[tt] = *(const bf16x8*)&Os[(tt*16 + l15)*136 + ks*32 + quad*8];
#pragma unroll
            for (int ct = 0; ct < 2; ++ct) {
                bf16x8 aw = *(const bf16x8*)&projw[(size_t)(wv*32 + ct*16 + l15)*128 + ks*32 + quad*8];
#pragma unroll
                for (int tt = 0; tt < 4; ++tt)
                    pa[ct][tt] = MFMA16(aw, bo[tt], pa[ct][tt]);
            }
        }
        float4 pb4[2], wn4[2], bn4[2];
#pragma unroll
        for (int ct = 0; ct < 2; ++ct) {
            const int ob = wv*32 + ct*16 + quad*4;
            pb4[ct] = *(const float4*)&projb[ob];
            wn4[ct] = *(const float4*)&n1wf[ob];
            bn4[ct] = *(const float4*)&n1bf[ob];
        }
        // LN pass 1: per-token wave-partial sums (this wave's 32 cols)
#pragma unroll
        for (int tt = 0; tt < 4; ++tt) {
            float sv = 0.f;
#pragma unroll
            for (int ct = 0; ct < 2; ++ct)
#pragma unroll
                for (int r = 0; r < 4; ++r) {
                    pa[ct][tt][r] += ((const float*)&pb4[ct])[r];
                    sv += pa[ct][tt][r];
                }
            sv += __shfl_xor(sv, 16);
            sv += __shfl_xor(sv, 32);
            if (quad == 0) psum[wv*64 + tt*16 + l15] = sv;
        }
        __syncthreads();
        float mu[4];
#pragma unroll
        for (int tt = 0; tt < 4; ++tt) {
            const int tok = tt*16 + l15;
            mu[tt] = (psum[tok] + psum[64+tok] + psum[128+tok] + psum[192+tok]) * (1.0f/128.0f);
            float sv = 0.f;
#pragma unroll
            for (int ct = 0; ct < 2; ++ct)
#pragma unroll
                for (int r = 0; r < 4; ++r) {
                    const float d = pa[ct][tt][r] - mu[tt];
                    sv += d*d;
                }
            sv += __shfl_xor(sv, 16);
            sv += __shfl_xor(sv, 32);
            if (quad == 0) pvar[wv*64 + tok] = sv;
        }
        __syncthreads();
#pragma unroll
        for (int tt = 0; tt < 4; ++tt) {
            const int tok = tt*16 + l15;
            const float var = (pvar[tok] + pvar[64+tok] + pvar[128+tok] + pvar[192+tok]) * (1.0f/128.0f);
            const float rstd = rsqrtf(var + 1e-5f);
#pragma unroll
            for (int ct = 0; ct < 2; ++ct) {
                const int ob = wv*32 + ct*16 + quad*4;
                bf16x4 xr = *(const bf16x4*)&Xs[tok*136 + ob];
                float xv[4];
#pragma unroll
                for (int r = 0; r < 4; ++r)
                    xv[r] = bf2f(xr[r]) + (pa[ct][tt][r] - mu[tt]) * rstd * ((const float*)&wn4[ct])[r]
                            + ((const float*)&bn4[ct])[r];
                pack4(xv[0], xv[1], xv[2], xv[3], &x1s[tok*136 + ob]);
            }
        }
    }
    __syncthreads();

    // ---- stage 6: MLP fc1+silu+fc2 (swapped, packed), hidden chunked 4x128 ----
    f32x4 ya[2][4];
#pragma unroll
    for (int ct = 0; ct < 2; ++ct)
#pragma unroll
        for (int tt = 0; tt < 4; ++tt) ya[ct][tt] = (f32x4){0.f, 0.f, 0.f, 0.f};

#pragma unroll
    for (int ch = 0; ch < 4; ++ch) {
        if (ch) __syncthreads();   // previous chunk's fc2 reads of hs must finish
        f32x4 ha[2][4];
#pragma unroll
        for (int ht = 0; ht < 2; ++ht)
#pragma unroll
            for (int tt = 0; tt < 4; ++tt) ha[ht][tt] = (f32x4){0.f, 0.f, 0.f, 0.f};
#pragma unroll
        for (int ks = 0; ks < 4; ++ks) {
            bf16x8 bx[4];
#pragma unroll
            for (int tt = 0; tt < 4; ++tt)
                bx[tt] = *(const bf16x8*)&x1s[(tt*16 + l15)*136 + ks*32 + quad*8];
#pragma unroll
            for (int ht = 0; ht < 2; ++ht) {
                bf16x8 aw = *(const bf16x8*)&fc1w[(size_t)(ch*128 + wv*32 + ht*16 + l15)*128 + ks*32 + quad*8];
#pragma unroll
                for (int tt = 0; tt < 4; ++tt)
                    ha[ht][tt] = MFMA16(aw, bx[tt], ha[ht][tt]);
            }
        }
#pragma unroll
        for (int ht = 0; ht < 2; ++ht) {
            const float4 bb4 = *(const float4*)&fc1bf[ch*128 + wv*32 + ht*16 + quad*4];
            const int hb = wv*32 + ht*16 + quad*4;
#pragma unroll
            for (int tt = 0; tt < 4; ++tt) {
                float hv[4];
#pragma unroll
                for (int r = 0; r < 4; ++r) {
                    float v = ha[ht][tt][r] + ((const float*)&bb4)[r];
                    hv[r] = v / (1.0f + __expf(-v));   // silu
                }
                pack4(hv[0], hv[1], hv[2], hv[3], &hs[(tt*16 + l15)*136 + hb]);
            }
        }
        __syncthreads();
#pragma unroll
        for (int ks = 0; ks < 4; ++ks) {
            bf16x8 bh[4];
#pragma unroll
            for (int tt = 0; tt < 4; ++tt)
                bh[tt] = *(const bf16x8*)&hs[(tt*16 + l15)*136 + ks*32 + quad*8];
#pragma unroll
            for (int ct = 0; ct < 2; ++ct) {
                bf16x8 aw = *(const bf16x8*)&fc2w[(size_t)(wv*32 + ct*16 + l15)*512 + ch*128 + ks*32 + quad*8];
#pragma unroll
                for (int tt = 0; tt < 4; ++tt)
                    ya[ct][tt] = MFMA16(aw, bh[tt], ya[ct][tt]);
            }
        }
    }
    __syncthreads();   // all fc2 reads of hs done before reuse as x2 staging

    // ---- stage 7: bias + LN2 + residual(x1s) -> x2s (overlays hs) ----
    {
        float4 pb4[2], wn4[2], bn4[2];
#pragma unroll
        for (int ct = 0; ct < 2; ++ct) {
            const int ob = wv*32 + ct*16 + quad*4;
            pb4[ct] = *(const float4*)&fc2bf[ob];
            wn4[ct] = *(const float4*)&n2wf[ob];
            bn4[ct] = *(const float4*)&n2bf[ob];
        }
#pragma unroll
        for (int tt = 0; tt < 4; ++tt) {
            float sv = 0.f;
#pragma unroll
            for (int ct = 0; ct < 2; ++ct)
#pragma unroll
                for (int r = 0; r < 4; ++r) {
                    ya[ct][tt][r] += ((const float*)&pb4[ct])[r];
                    sv += ya[ct][tt][r];
                }
            sv += __shfl_xor(sv, 16);
            sv += __shfl_xor(sv, 32);
            if (quad == 0) psum[wv*64 + tt*16 + l15] = sv;
        }
        __syncthreads();
        float mu[4];
#pragma unroll
        for (int tt = 0; tt < 4; ++tt) {
            const int tok = tt*16 + l15;
            mu[tt] = (psum[tok] + psum[64+tok] + psum[128+tok] + psum[192+tok]) * (1.0f/128.0f);
            float sv = 0.f;
#pragma unroll
            for (int ct = 0; ct < 2; ++ct)
#pragma unroll
                for (int r = 0; r < 4; ++r) {
                    const float d = ya[ct][tt][r] - mu[tt];
                    sv += d*d;
                }
            sv += __shfl_xor(sv, 16);
            sv += __shfl_xor(sv, 32);
            if (quad == 0) pvar[wv*64 + tok] = sv;
        }
        __syncthreads();
        bf16* x2s = hs;
#pragma unroll
        for (int tt = 0; tt < 4; ++tt) {
            const int tok = tt*16 + l15;
            const float var = (pvar[tok] + pvar[64+tok] + pvar[128+tok] + pvar[192+tok]) * (1.0f/128.0f);
            const float rstd = rsqrtf(var + 1e-5f);
#pragma unroll
            for (int ct = 0; ct < 2; ++ct) {
                const int ob = wv*32 + ct*16 + quad*4;
                bf16x4 xr = *(const bf16x4*)&x1s[tok*136 + ob];
                float xv[4];
#pragma unroll
                for (int r = 0; r < 4; ++r)
                    xv[r] = bf2f(xr[r]) + (ya[ct][tt][r] - mu[tt]) * rstd * ((const float*)&wn4[ct])[r]
                            + ((const float*)&bn4[ct])[r];
                pack4(xv[0], xv[1], xv[2], xv[3], &x2s[tok*136 + ob]);
            }
        }
    }
    __syncthreads();

    // ---- stage 8: write x2 to planar (B, C, H, W) at reverse-shifted positions ----
    {
        const bf16* x2s = hs;
        const int wf0 = ww*8 + 4;
        const int wf1 = (ww*8 + 8) & 127;
#pragma unroll
        for (int g = 0; g < 4; ++g) {
            const int idx = g*256 + tid;          // 0..1023 = (rr, c)
            const int c  = idx & 127;             // lane-consecutive c -> conflict-free LDS reads
            const int rr = idx >> 7;              // covers 0..7 over the 4 iterations x 2 halves
            const int hf = (wh*8 + rr + 4) & 127;
            const size_t rowb = ((size_t)(b*128 + c))*16384 + (size_t)hf*128;
            if (!isf) {
                const unsigned short* xu = (const unsigned short*)x2s;
                uint2 u0, u1;
                u0.x = (unsigned)xu[(rr*8+0)*136 + c] | ((unsigned)xu[(rr*8+1)*136 + c] << 16);
                u0.y = (unsigned)xu[(rr*8+2)*136 + c] | ((unsigned)xu[(rr*8+3)*136 + c] << 16);
                u1.x = (unsigned)xu[(rr*8+4)*136 + c] | ((unsigned)xu[(rr*8+5)*136 + c] << 16);
                u1.y = (unsigned)xu[(rr*8+6)*136 + c] | ((unsigned)xu[(rr*8+7)*136 + c] << 16);
                bf16* dstb = (bf16*)out;
                *(uint2*)(dstb + rowb + wf0) = u0;
                *(uint2*)(dstb + rowb + wf1) = u1;
            } else {
                float4 u0, u1;
                u0.x = bf2f(x2s[(rr*8+0)*136 + c]); u0.y = bf2f(x2s[(rr*8+1)*136 + c]);
                u0.z = bf2f(x2s[(rr*8+2)*136 + c]); u0.w = bf2f(x2s[(rr*8+3)*136 + c]);
                u1.x = bf2f(x2s[(rr*8+4)*136 + c]); u1.y = bf2f(x2s[(rr*8+5)*136 + c]);
                u1.z = bf2f(x2s[(rr*8+6)*136 + c]); u1.w = bf2f(x2s[(rr*8+7)*136 + c]);
                float* dstf = (float*)out;
                *(float4*)(dstf + rowb + wf0) = u0;
                *(float4*)(dstf + rowb + wf1) = u1;
            }
        }
    }
}

extern "C" void kernel_launch(void* const* d_in, const int* in_sizes, int n_in,
                              void* d_out, int out_size, void* d_ws, size_t ws_size,
                              hipStream_t stream)
{
    (void)in_sizes; (void)n_in; (void)out_size; (void)ws_size;
    const void* x      = d_in[0];
    const void* n1w    = d_in[1];
    const void* n1b    = d_in[2];
    const void* qkv_w  = d_in[3];
    const void* q_bias = d_in[4];
    const void* v_bias = d_in[5];
    const void* lscale = d_in[6];
    const void* cpb_w1 = d_in[7];
    const void* cpb_b1 = d_in[8];
    const void* cpb_w2 = d_in[9];
    const void* proj_w = d_in[10];
    const void* proj_b = d_in[11];
    const void* n2w    = d_in[12];
    const void* n2b    = d_in[13];
    const void* fc1w   = d_in[14];
    const void* fc1b   = d_in[15];
    const void* fc2w   = d_in[16];
    const void* fc2b   = d_in[17];

    char*  ws      = (char*)d_ws;
    float* biasAll = (float*)ws;                      // 64 KiB @ 0
    float* scales  = (float*)(ws + OFF_SCALES);
    int*   flag    = (int*)(ws + OFF_FLAG);

    k_init<<<dim3(97), dim3(256), 0, stream>>>(cpb_w1, cpb_b1, cpb_w2, lscale,
                                               qkv_w, proj_w, fc1w, fc2w,
                                               q_bias, v_bias, proj_b, n1w, n1b,
                                               fc1b, fc2b, n2w, n2b, ws);
    k_fused<<<dim3(4096), dim3(256), 0, stream>>>(x,
        (const bf16*)(ws + OFF_QKVW), (const float*)(ws + OFF_QKVB),
        (const bf16*)(ws + OFF_PROJW), (const float*)(ws + OFF_PROJB),
        (const float*)(ws + OFF_N1W), (const float*)(ws + OFF_N1B),
        (const bf16*)(ws + OFF_FC1W), (const float*)(ws + OFF_FC1B),
        (const bf16*)(ws + OFF_FC2W), (const float*)(ws + OFF_FC2B),
        (const float*)(ws + OFF_N2W), (const float*)(ws + OFF_N2B),
        biasAll, scales, flag, d_out);
}